// Round 1
// baseline (822.197 us; speedup 1.0000x reference)
//
#include <hip/hip_runtime.h>
#include <hip/hip_bf16.h>

typedef unsigned short ushort_t;
using bf16x8 = __attribute__((ext_vector_type(8))) short;
using f32x4  = __attribute__((ext_vector_type(4))) float;

#define DEV __device__ __forceinline__

DEV unsigned short f2bf(float f) {
    unsigned int u = __builtin_bit_cast(unsigned int, f);
    u = (u + 0x7fffu + ((u >> 16) & 1u)) >> 16;
    return (unsigned short)u;
}

DEV void gload16(const unsigned short* g, unsigned short* l) {
    __builtin_amdgcn_global_load_lds(
        (const __attribute__((address_space(1))) void*)g,
        (__attribute__((address_space(3))) void*)l, 16, 0, 0);
}

// ---------------- f32 -> bf16 convert ----------------
__global__ __launch_bounds__(256) void cvtbf_kernel(const float* __restrict__ in,
                                                    unsigned short* __restrict__ out) {
    int i = (blockIdx.x * 256 + threadIdx.x) * 4;
    float4 v = *(const float4*)&in[i];
    out[i + 0] = f2bf(v.x);
    out[i + 1] = f2bf(v.y);
    out[i + 2] = f2bf(v.z);
    out[i + 3] = f2bf(v.w);
}

// ---------------- transpose + convert: in[R,C] f32 -> out[C,R] bf16 ----------------
__global__ __launch_bounds__(256) void transpose_cvt_kernel(const float* __restrict__ in,
                                                            unsigned short* __restrict__ out,
                                                            int R, int C) {
    __shared__ float t[32][33];
    int tx = threadIdx.x, ty = threadIdx.y;
    int c0 = blockIdx.x * 32, r0 = blockIdx.y * 32;
#pragma unroll
    for (int i = 0; i < 4; ++i)
        t[ty + i * 8][tx] = in[(size_t)(r0 + ty + i * 8) * C + c0 + tx];
    __syncthreads();
#pragma unroll
    for (int i = 0; i < 4; ++i)
        out[(size_t)(c0 + ty + i * 8) * R + r0 + tx] = f2bf(t[tx][ty + i * 8]);
}

// ---------------- GEMM: A[M,K]bf16 @ Bt[N,K]bf16^T + bias -> out ----------------
// 128x128 tile, BK=64, 4 waves (2x2), 16x16x32 bf16 MFMA.
// LDS chunk layout: chunk ci = kb*128 + row holds A[row][kb*8..kb*8+7] (16B).
// global_load_lds with linear LDS dest; per-lane global source supplies the mapping.
template <int ACT, int OBF>
__global__ __launch_bounds__(256) void gemm_kernel(const unsigned short* __restrict__ A,
                                                   const unsigned short* __restrict__ Bt,
                                                   const float* __restrict__ bias,
                                                   void* __restrict__ out,
                                                   int M, int N, int K) {
    __shared__ unsigned short lA[128 * 64];
    __shared__ unsigned short lB[128 * 64];
    const int tid = threadIdx.x;
    const int lane = tid & 63, w = tid >> 6;
    const int wm = w >> 1, wn = w & 1;
    const int g = lane >> 4, lr = lane & 15;
    const int m0 = blockIdx.y * 128, n0 = blockIdx.x * 128;

    f32x4 acc[4][4] = {};
    const int nkt = K >> 6;
    for (int kt = 0; kt < nkt; ++kt) {
        __syncthreads();
        const int k0 = kt << 6;
#pragma unroll
        for (int i = 0; i < 4; ++i) {
            int ci = i * 256 + w * 64 + lane;  // 0..1023
            int row = ci & 127, kb = ci >> 7;
            gload16(&A[(size_t)(m0 + row) * K + k0 + kb * 8], &lA[(size_t)(i * 256 + w * 64) * 8]);
            gload16(&Bt[(size_t)(n0 + row) * K + k0 + kb * 8], &lB[(size_t)(i * 256 + w * 64) * 8]);
        }
        __syncthreads();
#pragma unroll
        for (int ks = 0; ks < 2; ++ks) {
            bf16x8 af[4], bfr[4];
#pragma unroll
            for (int mf = 0; mf < 4; ++mf) {
                int ci = (ks * 4 + g) * 128 + wm * 64 + mf * 16 + lr;
                af[mf] = *(const bf16x8*)&lA[ci * 8];
            }
#pragma unroll
            for (int nf = 0; nf < 4; ++nf) {
                int ci = (ks * 4 + g) * 128 + wn * 64 + nf * 16 + lr;
                bfr[nf] = *(const bf16x8*)&lB[ci * 8];
            }
#pragma unroll
            for (int mf = 0; mf < 4; ++mf)
#pragma unroll
                for (int nf = 0; nf < 4; ++nf)
                    acc[mf][nf] = __builtin_amdgcn_mfma_f32_16x16x32_bf16(af[mf], bfr[nf],
                                                                          acc[mf][nf], 0, 0, 0);
        }
    }
#pragma unroll
    for (int mf = 0; mf < 4; ++mf) {
#pragma unroll
        for (int nf = 0; nf < 4; ++nf) {
            int col = n0 + wn * 64 + nf * 16 + lr;
            float bv = bias[col];
#pragma unroll
            for (int r = 0; r < 4; ++r) {
                int row = m0 + wm * 64 + mf * 16 + g * 4 + r;
                float v = acc[mf][nf][r] + bv;
                if (ACT == 1) v = 0.5f * v * (1.0f + erff(v * 0.70710678118f));
                if (OBF)
                    ((unsigned short*)out)[(size_t)row * N + col] = f2bf(v);
                else
                    ((float*)out)[(size_t)row * N + col] = v;
            }
        }
    }
}

// ---------------- flash attention: qkv[B*T,3C]bf16 -> y[B*T,C]bf16 ----------------
__global__ __launch_bounds__(256) void attn_kernel(const unsigned short* __restrict__ qkv,
                                                   unsigned short* __restrict__ y) {
    __shared__ unsigned short Kl[64 * 72];
    __shared__ unsigned short Vt[64 * 72];
    __shared__ unsigned short Pl[4][16 * 72];
    const int tid = threadIdx.x, lane = tid & 63, w = tid >> 6;
    const int g = lane >> 4, lr = lane & 15;
    const int qt = blockIdx.x, h = blockIdx.y, b = blockIdx.z;
    const size_t rs3 = 3072;
    const unsigned short* qbase = qkv + (size_t)b * 2048 * rs3 + h * 64;
    const unsigned short* kbase = qbase + 1024;
    const unsigned short* vbase = qbase + 2048;
    const int q0 = qt * 64 + w * 16;

    bf16x8 qf[2];
#pragma unroll
    for (int f = 0; f < 2; ++f)
        qf[f] = *(const bf16x8*)&qbase[(size_t)(q0 + lr) * rs3 + f * 32 + g * 8];

    f32x4 O[4] = {};
    float mreg[4], lsum[4];
#pragma unroll
    for (int r = 0; r < 4; ++r) { mreg[r] = -1e30f; lsum[r] = 0.f; }

    for (int kt = 0; kt <= qt; ++kt) {
        __syncthreads();
        {
            int cid0 = tid * 2;
#pragma unroll
            for (int c = 0; c < 2; ++c) {
                int cid = cid0 + c;
                int row = cid >> 3, cc = cid & 7;
                bf16x8 kv = *(const bf16x8*)&kbase[(size_t)(kt * 64 + row) * rs3 + cc * 8];
                *(bf16x8*)&Kl[row * 72 + cc * 8] = kv;
                bf16x8 vv = *(const bf16x8*)&vbase[(size_t)(kt * 64 + row) * rs3 + cc * 8];
#pragma unroll
                for (int j = 0; j < 8; ++j)
                    Vt[(cc * 8 + j) * 72 + row] = (unsigned short)vv[j];
            }
        }
        __syncthreads();
        f32x4 s[4];
#pragma unroll
        for (int st = 0; st < 4; ++st) {
            f32x4 a = {};
#pragma unroll
            for (int f = 0; f < 2; ++f) {
                bf16x8 kf = *(const bf16x8*)&Kl[(st * 16 + lr) * 72 + f * 32 + g * 8];
                a = __builtin_amdgcn_mfma_f32_16x16x32_bf16(qf[f], kf, a, 0, 0, 0);
            }
            s[st] = a;
        }
#pragma unroll
        for (int st = 0; st < 4; ++st) {
            int key = kt * 64 + st * 16 + lr;
#pragma unroll
            for (int r = 0; r < 4; ++r) {
                int q = q0 + g * 4 + r;
                float v = s[st][r] * 0.125f;
                s[st][r] = (key <= q) ? v : -1e30f;
            }
        }
        float alpha[4];
#pragma unroll
        for (int r = 0; r < 4; ++r) {
            float v = fmaxf(fmaxf(s[0][r], s[1][r]), fmaxf(s[2][r], s[3][r]));
            v = fmaxf(v, __shfl_xor(v, 1));
            v = fmaxf(v, __shfl_xor(v, 2));
            v = fmaxf(v, __shfl_xor(v, 4));
            v = fmaxf(v, __shfl_xor(v, 8));
            float mn = fmaxf(mreg[r], v);
            alpha[r] = __expf(mreg[r] - mn);
            mreg[r] = mn;
        }
#pragma unroll
        for (int r = 0; r < 4; ++r) {
            float rsum = 0.f;
#pragma unroll
            for (int st = 0; st < 4; ++st) {
                float p = __expf(s[st][r] - mreg[r]);
                s[st][r] = p;
                rsum += p;
            }
            rsum += __shfl_xor(rsum, 1);
            rsum += __shfl_xor(rsum, 2);
            rsum += __shfl_xor(rsum, 4);
            rsum += __shfl_xor(rsum, 8);
            lsum[r] = lsum[r] * alpha[r] + rsum;
#pragma unroll
            for (int dt = 0; dt < 4; ++dt) O[dt][r] *= alpha[r];
        }
#pragma unroll
        for (int st = 0; st < 4; ++st)
#pragma unroll
            for (int r = 0; r < 4; ++r)
                Pl[w][(g * 4 + r) * 72 + st * 16 + lr] = f2bf(s[st][r]);
        __syncthreads();
#pragma unroll
        for (int ks = 0; ks < 2; ++ks) {
            bf16x8 pa = *(const bf16x8*)&Pl[w][lr * 72 + ks * 32 + g * 8];
#pragma unroll
            for (int dt = 0; dt < 4; ++dt) {
                bf16x8 vf = *(const bf16x8*)&Vt[(dt * 16 + lr) * 72 + ks * 32 + g * 8];
                O[dt] = __builtin_amdgcn_mfma_f32_16x16x32_bf16(pa, vf, O[dt], 0, 0, 0);
            }
        }
    }
#pragma unroll
    for (int dt = 0; dt < 4; ++dt) {
#pragma unroll
        for (int r = 0; r < 4; ++r) {
            int q = q0 + g * 4 + r;
            float v = O[dt][r] / lsum[r];
            y[(size_t)(b * 2048 + q) * 1024 + h * 64 + dt * 16 + lr] = f2bf(v);
        }
    }
}

// ---------------- residual + layernorm: out = base + LN(delta)*g+b ----------------
template <int WRITE_BF>
__global__ __launch_bounds__(256) void ln_kernel(const float* __restrict__ base,
                                                 const float* __restrict__ delta,
                                                 const float* __restrict__ gw,
                                                 const float* __restrict__ bw,
                                                 float* __restrict__ outf,
                                                 unsigned short* __restrict__ outb) {
    const int row = blockIdx.x;
    const int tid = threadIdx.x;
    const float* d = delta + (size_t)row * 1024;
    const float* bs = base + (size_t)row * 1024;
    float4 x = *(const float4*)&d[tid * 4];
    float s = x.x + x.y + x.z + x.w;
    float s2 = x.x * x.x + x.y * x.y + x.z * x.z + x.w * x.w;
#pragma unroll
    for (int off = 1; off < 64; off <<= 1) {
        s += __shfl_xor(s, off);
        s2 += __shfl_xor(s2, off);
    }
    __shared__ float red[8];
    if ((tid & 63) == 0) {
        red[tid >> 6] = s;
        red[4 + (tid >> 6)] = s2;
    }
    __syncthreads();
    s = red[0] + red[1] + red[2] + red[3];
    s2 = red[4] + red[5] + red[6] + red[7];
    float mu = s * (1.f / 1024.f);
    float var = s2 * (1.f / 1024.f) - mu * mu;
    float rsig = rsqrtf(var + 1e-5f);
    float4 bb = *(const float4*)&bs[tid * 4];
    float4 gv = *(const float4*)&gw[tid * 4];
    float4 bv = *(const float4*)&bw[tid * 4];
    float4 o;
    o.x = bb.x + (x.x - mu) * rsig * gv.x + bv.x;
    o.y = bb.y + (x.y - mu) * rsig * gv.y + bv.y;
    o.z = bb.z + (x.z - mu) * rsig * gv.z + bv.z;
    o.w = bb.w + (x.w - mu) * rsig * gv.w + bv.w;
    *(float4*)&outf[(size_t)row * 1024 + tid * 4] = o;
    if (WRITE_BF) {
        unsigned short* ob = outb + (size_t)row * 1024 + tid * 4;
        ob[0] = f2bf(o.x);
        ob[1] = f2bf(o.y);
        ob[2] = f2bf(o.z);
        ob[3] = f2bf(o.w);
    }
}

extern "C" void kernel_launch(void* const* d_in, const int* in_sizes, int n_in,
                              void* d_out, int out_size, void* d_ws, size_t ws_size,
                              hipStream_t stream) {
    const float* x = (const float*)d_in[0];
    const float* w_qkv = (const float*)d_in[1];
    const float* b_qkv = (const float*)d_in[2];
    const float* w_out = (const float*)d_in[3];
    const float* b_out = (const float*)d_in[4];
    const float* w1 = (const float*)d_in[5];
    const float* b1 = (const float*)d_in[6];
    const float* w2 = (const float*)d_in[7];
    const float* b2 = (const float*)d_in[8];
    const float* g1 = (const float*)d_in[9];
    const float* be1 = (const float*)d_in[10];
    const float* g2 = (const float*)d_in[11];
    const float* be2 = (const float*)d_in[12];

    const size_t MB = 1ull << 20;
    if (ws_size < 184 * MB) return;
    char* ws = (char*)d_ws;
    unsigned short* xb    = (unsigned short*)(ws + 0);         // 16MB
    unsigned short* wqkvt = (unsigned short*)(ws + 16 * MB);   // 6MB
    unsigned short* qkvb  = (unsigned short*)(ws + 22 * MB);   // 48MB
    unsigned short* hb    = (unsigned short*)(ws + 0);         // 64MB (reuse)
    unsigned short* woutt = (unsigned short*)(ws + 70 * MB);   // 2MB
    unsigned short* yb    = (unsigned short*)(ws + 72 * MB);   // 16MB
    float*          attnp = (float*)(ws + 88 * MB);            // 32MB
    float*          ff    = (float*)(ws + 88 * MB);            // 32MB (reuse)
    float*          x2f   = (float*)(ws + 120 * MB);           // 32MB
    unsigned short* x2b   = (unsigned short*)(ws + 152 * MB);  // 16MB
    unsigned short* w1t   = (unsigned short*)(ws + 168 * MB);  // 8MB
    unsigned short* w2t   = (unsigned short*)(ws + 176 * MB);  // 8MB

    // prep
    cvtbf_kernel<<<8192, 256, 0, stream>>>(x, xb);
    transpose_cvt_kernel<<<dim3(96, 32), dim3(32, 8), 0, stream>>>(w_qkv, wqkvt, 1024, 3072);
    transpose_cvt_kernel<<<dim3(32, 32), dim3(32, 8), 0, stream>>>(w_out, woutt, 1024, 1024);
    transpose_cvt_kernel<<<dim3(128, 32), dim3(32, 8), 0, stream>>>(w1, w1t, 1024, 4096);
    transpose_cvt_kernel<<<dim3(32, 128), dim3(32, 8), 0, stream>>>(w2, w2t, 4096, 1024);
    // qkv = x @ w_qkv + b_qkv  (bf16 out)
    gemm_kernel<0, 1><<<dim3(24, 64), 256, 0, stream>>>(xb, wqkvt, b_qkv, qkvb, 8192, 3072, 1024);
    // attention
    attn_kernel<<<dim3(32, 16, 4), 256, 0, stream>>>(qkvb, yb);
    // out proj (f32 out)
    gemm_kernel<0, 0><<<dim3(8, 64), 256, 0, stream>>>(yb, woutt, b_out, attnp, 8192, 1024, 1024);
    // x2 = x + LN(attnp)
    ln_kernel<1><<<8192, 256, 0, stream>>>(x, attnp, g1, be1, x2f, x2b);
    // h = gelu(x2 @ w1 + b1) (bf16 out)
    gemm_kernel<1, 1><<<dim3(32, 64), 256, 0, stream>>>(x2b, w1t, b1, hb, 8192, 4096, 1024);
    // f = h @ w2 + b2 (f32 out)
    gemm_kernel<0, 0><<<dim3(8, 64), 256, 0, stream>>>(hb, w2t, b2, ff, 8192, 1024, 4096);
    // out = x2 + LN(f)
    ln_kernel<0><<<8192, 256, 0, stream>>>(x2f, ff, g2, be2, (float*)d_out, nullptr);
}

// Round 2
// 765.692 us; speedup vs baseline: 1.0738x; 1.0738x over previous
//
#include <hip/hip_runtime.h>
#include <hip/hip_bf16.h>

typedef unsigned short ushort_t;
using bf16x8 = __attribute__((ext_vector_type(8))) short;
using f32x4  = __attribute__((ext_vector_type(4))) float;

#define DEV __device__ __forceinline__

DEV unsigned short f2bf(float f) {
    unsigned int u = __builtin_bit_cast(unsigned int, f);
    u = (u + 0x7fffu + ((u >> 16) & 1u)) >> 16;
    return (unsigned short)u;
}

DEV int cvtpk_bf16(float lo, float hi) {
    int r;
    asm("v_cvt_pk_bf16_f32 %0, %1, %2" : "=v"(r) : "v"(lo), "v"(hi));
    return r;
}

DEV void gload16(const unsigned short* g, unsigned short* l) {
    __builtin_amdgcn_global_load_lds(
        (const __attribute__((address_space(1))) void*)g,
        (__attribute__((address_space(3))) void*)l, 16, 0, 0);
}

// ---------------- f32 -> bf16 convert ----------------
__global__ __launch_bounds__(256) void cvtbf_kernel(const float* __restrict__ in,
                                                    unsigned short* __restrict__ out) {
    int i = (blockIdx.x * 256 + threadIdx.x) * 4;
    float4 v = *(const float4*)&in[i];
    out[i + 0] = f2bf(v.x);
    out[i + 1] = f2bf(v.y);
    out[i + 2] = f2bf(v.z);
    out[i + 3] = f2bf(v.w);
}

// ---------------- transpose + convert: in[R,C] f32 -> out[C,R] bf16 ----------------
__global__ __launch_bounds__(256) void transpose_cvt_kernel(const float* __restrict__ in,
                                                            unsigned short* __restrict__ out,
                                                            int R, int C) {
    __shared__ float t[32][33];
    int tx = threadIdx.x, ty = threadIdx.y;
    int c0 = blockIdx.x * 32, r0 = blockIdx.y * 32;
#pragma unroll
    for (int i = 0; i < 4; ++i)
        t[ty + i * 8][tx] = in[(size_t)(r0 + ty + i * 8) * C + c0 + tx];
    __syncthreads();
#pragma unroll
    for (int i = 0; i < 4; ++i)
        out[(size_t)(c0 + ty + i * 8) * R + r0 + tx] = f2bf(t[tx][ty + i * 8]);
}

// ---------------- GEMM: A[M,K]bf16 @ Bt[N,K]bf16^T + bias -> out ----------------
template <int ACT, int OBF>
__global__ __launch_bounds__(256) void gemm_kernel(const unsigned short* __restrict__ A,
                                                   const unsigned short* __restrict__ Bt,
                                                   const float* __restrict__ bias,
                                                   void* __restrict__ out,
                                                   int M, int N, int K) {
    __shared__ unsigned short lA[128 * 64];
    __shared__ unsigned short lB[128 * 64];
    const int tid = threadIdx.x;
    const int lane = tid & 63, w = tid >> 6;
    const int wm = w >> 1, wn = w & 1;
    const int g = lane >> 4, lr = lane & 15;
    const int m0 = blockIdx.y * 128, n0 = blockIdx.x * 128;

    f32x4 acc[4][4] = {};
    const int nkt = K >> 6;
    for (int kt = 0; kt < nkt; ++kt) {
        __syncthreads();
        const int k0 = kt << 6;
#pragma unroll
        for (int i = 0; i < 4; ++i) {
            int ci = i * 256 + w * 64 + lane;  // 0..1023
            int row = ci & 127, kb = ci >> 7;
            gload16(&A[(size_t)(m0 + row) * K + k0 + kb * 8], &lA[(size_t)(i * 256 + w * 64) * 8]);
            gload16(&Bt[(size_t)(n0 + row) * K + k0 + kb * 8], &lB[(size_t)(i * 256 + w * 64) * 8]);
        }
        __syncthreads();
#pragma unroll
        for (int ks = 0; ks < 2; ++ks) {
            bf16x8 af[4], bfr[4];
#pragma unroll
            for (int mf = 0; mf < 4; ++mf) {
                int ci = (ks * 4 + g) * 128 + wm * 64 + mf * 16 + lr;
                af[mf] = *(const bf16x8*)&lA[ci * 8];
            }
#pragma unroll
            for (int nf = 0; nf < 4; ++nf) {
                int ci = (ks * 4 + g) * 128 + wn * 64 + nf * 16 + lr;
                bfr[nf] = *(const bf16x8*)&lB[ci * 8];
            }
#pragma unroll
            for (int mf = 0; mf < 4; ++mf)
#pragma unroll
                for (int nf = 0; nf < 4; ++nf)
                    acc[mf][nf] = __builtin_amdgcn_mfma_f32_16x16x32_bf16(af[mf], bfr[nf],
                                                                          acc[mf][nf], 0, 0, 0);
        }
    }
#pragma unroll
    for (int mf = 0; mf < 4; ++mf) {
#pragma unroll
        for (int nf = 0; nf < 4; ++nf) {
            int col = n0 + wn * 64 + nf * 16 + lr;
            float bv = bias[col];
#pragma unroll
            for (int r = 0; r < 4; ++r) {
                int row = m0 + wm * 64 + mf * 16 + g * 4 + r;
                float v = acc[mf][nf][r] + bv;
                if (ACT == 1) v = 0.5f * v * (1.0f + erff(v * 0.70710678118f));
                if (OBF)
                    ((unsigned short*)out)[(size_t)row * N + col] = f2bf(v);
                else
                    ((float*)out)[(size_t)row * N + col] = v;
            }
        }
    }
}

// ---------------- flash attention v2: qkv[B*T,3C]bf16 -> y[B*T,C]bf16 ----------------
// 128 q-rows/block, 4 waves x 32 q-rows (2x16 subtiles). Swapped QK^T
// (mfma(K,Q) -> S^T: lane (g,lr) holds S[q=lr][k=st*16+g*4+r]); softmax fully
// in-register; P packed via v_cvt_pk_bf16_f32 + ds_bpermute to the PV
// A-fragment layout. K and V^T staged in XOR-swizzled [64][64] LDS tiles.
__global__ __launch_bounds__(256) void attn_kernel(const unsigned short* __restrict__ qkv,
                                                   unsigned short* __restrict__ y) {
    __shared__ unsigned short Kl[64 * 64];
    __shared__ unsigned short Vt[64 * 64];
    const int tid = threadIdx.x, lane = tid & 63, w = tid >> 6;
    const int g = lane >> 4, lr = lane & 15;
    const int J = 15 - blockIdx.x;  // reversed: long blocks first
    const int h = blockIdx.y, b = blockIdx.z;
    const size_t rs3 = 3072;
    const unsigned short* qbase = qkv + (size_t)b * 2048 * rs3 + h * 64;
    const unsigned short* kbase = qbase + 1024;
    const unsigned short* vbase = qbase + 2048;
    const int q0w = J * 128 + w * 32;

    // Q fragments, pre-scaled by 0.125*log2(e) (exp2-domain softmax)
    const float qscale = 0.125f * 1.44269504089f;
    int qf[2][2][4];
#pragma unroll
    for (int sub = 0; sub < 2; ++sub)
#pragma unroll
        for (int f = 0; f < 2; ++f) {
            int4 v = *(const int4*)&qbase[(size_t)(q0w + sub * 16 + lr) * rs3 + f * 32 + g * 8];
            int vv[4] = {v.x, v.y, v.z, v.w};
#pragma unroll
            for (int i = 0; i < 4; ++i) {
                unsigned int u = (unsigned int)vv[i];
                float lo = __builtin_bit_cast(float, u << 16) * qscale;
                float hi = __builtin_bit_cast(float, u & 0xffff0000u) * qscale;
                qf[sub][f][i] = cvtpk_bf16(lo, hi);
            }
        }

    f32x4 O[2][4] = {};
    float m_[2] = {-3.0e38f, -3.0e38f}, l_[2] = {0.f, 0.f};
    // bpermute byte-index vectors
    const int idxP0 = 4 * (32 * (g & 1) + lr);
    const int idxP1 = idxP0 + 64;
    int idxA[4];
#pragma unroll
    for (int r = 0; r < 4; ++r) idxA[r] = 4 * (g * 20 + r);
    const bool ghigh = (g >> 1) != 0;

    const int ktend = 2 * J + 2;
    for (int kt = 0; kt < ktend; ++kt) {
        // global loads issued before barrier (latency hides under barrier wait)
        int4 kc[2], vc[2];
#pragma unroll
        for (int c = 0; c < 2; ++c) {
            int cid = c * 256 + tid;
            int row = cid >> 3, cc = cid & 7;
            kc[c] = *(const int4*)&kbase[(size_t)(kt * 64 + row) * rs3 + cc * 8];
            vc[c] = *(const int4*)&vbase[(size_t)(kt * 64 + row) * rs3 + cc * 8];
        }
        __syncthreads();
#pragma unroll
        for (int c = 0; c < 2; ++c) {
            int cid = c * 256 + tid;
            int row = cid >> 3, cc = cid & 7;
            int xk = cc ^ (row & 7) ^ (row >> 3);
            *(int4*)&Kl[row * 64 + xk * 8] = kc[c];
            unsigned int uw[4] = {(unsigned int)vc[c].x, (unsigned int)vc[c].y,
                                  (unsigned int)vc[c].z, (unsigned int)vc[c].w};
#pragma unroll
            for (int j = 0; j < 8; ++j) {
                unsigned short val = (j & 1) ? (unsigned short)(uw[j >> 1] >> 16)
                                             : (unsigned short)(uw[j >> 1] & 0xffffu);
                int d = cc * 8 + j;
                int xv = (row >> 3) ^ j ^ cc;
                Vt[d * 64 + xv * 8 + (row & 7)] = val;
            }
        }
        __syncthreads();

        const bool act0 = (kt * 64) <= (q0w + 15);
        const bool act1 = (kt * 64) <= (q0w + 31);

        // QK^T swapped: S^T tiles
        f32x4 s0[4], s1[4];
#pragma unroll
        for (int st = 0; st < 4; ++st) {
            int rbase = (st * 16 + lr) * 64;
            int sw = (lr & 7) ^ (st * 2 + (lr >> 3));
            bf16x8 kf0 = *(const bf16x8*)&Kl[rbase + ((g ^ sw) * 8)];
            bf16x8 kf1 = *(const bf16x8*)&Kl[rbase + (((4 + g) ^ sw) * 8)];
            if (act0) {
                f32x4 a = {};
                a = __builtin_amdgcn_mfma_f32_16x16x32_bf16(kf0, *(const bf16x8*)&qf[0][0], a, 0, 0, 0);
                a = __builtin_amdgcn_mfma_f32_16x16x32_bf16(kf1, *(const bf16x8*)&qf[0][1], a, 0, 0, 0);
                s0[st] = a;
            }
            if (act1) {
                f32x4 a = {};
                a = __builtin_amdgcn_mfma_f32_16x16x32_bf16(kf0, *(const bf16x8*)&qf[1][0], a, 0, 0, 0);
                a = __builtin_amdgcn_mfma_f32_16x16x32_bf16(kf1, *(const bf16x8*)&qf[1][1], a, 0, 0, 0);
                s1[st] = a;
            }
        }

        int wt0[2][4], wt1[2][4];
#pragma unroll
        for (int sub = 0; sub < 2; ++sub) {
            if (sub == 0 && !act0) continue;
            if (sub == 1 && !act1) continue;
            f32x4* s = (sub == 0) ? s0 : s1;
            const int qmin = q0w + sub * 16;
            if (kt * 64 + 63 > qmin) {  // diagonal tile: apply causal mask
                int qv = qmin + lr;
#pragma unroll
                for (int st = 0; st < 4; ++st) {
                    int keyb = kt * 64 + st * 16 + g * 4;
#pragma unroll
                    for (int r = 0; r < 4; ++r)
                        if (keyb + r > qv) s[st][r] = -3.0e38f;
                }
            }
            // row max (q = lr; k spread over regs + groups)
            float mx = fmaxf(fmaxf(s[0][0], s[0][1]), fmaxf(s[0][2], s[0][3]));
#pragma unroll
            for (int st = 1; st < 4; ++st)
                mx = fmaxf(mx, fmaxf(fmaxf(s[st][0], s[st][1]), fmaxf(s[st][2], s[st][3])));
            mx = fmaxf(mx, __shfl_xor(mx, 16));
            mx = fmaxf(mx, __shfl_xor(mx, 32));
            float mold = m_[sub];
            float mnew = fmaxf(mold, mx);
            float alpha = __builtin_amdgcn_exp2f(mold - mnew);
            m_[sub] = mnew;
            float rs = 0.f;
#pragma unroll
            for (int st = 0; st < 4; ++st)
#pragma unroll
                for (int r = 0; r < 4; ++r) {
                    float p = __builtin_amdgcn_exp2f(s[st][r] - mnew);
                    s[st][r] = p;
                    rs += p;
                }
            rs += __shfl_xor(rs, 16);
            rs += __shfl_xor(rs, 32);
            l_[sub] = l_[sub] * alpha + rs;
            // redistribute alpha to O-row layout (q = g*4+r)
            int av = __builtin_bit_cast(int, alpha);
            f32x4* Os = O[sub];
#pragma unroll
            for (int r = 0; r < 4; ++r) {
                float ar = __builtin_bit_cast(float, __builtin_amdgcn_ds_bpermute(idxA[r], av));
#pragma unroll
                for (int dt = 0; dt < 4; ++dt) Os[dt][r] *= ar;
            }
            // pack P to bf16 pairs, redistribute to A-fragment layout
            int ws[4][2];
#pragma unroll
            for (int st = 0; st < 4; ++st) {
                ws[st][0] = cvtpk_bf16(s[st][0], s[st][1]);
                ws[st][1] = cvtpk_bf16(s[st][2], s[st][3]);
            }
            int(*wt)[4] = (sub == 0) ? wt0 : wt1;
#pragma unroll
            for (int ks = 0; ks < 2; ++ks)
#pragma unroll
                for (int hp = 0; hp < 4; ++hp) {
                    int idx = (hp < 2) ? idxP0 : idxP1;
                    int v0 = __builtin_amdgcn_ds_bpermute(idx, ws[2 * ks][hp & 1]);
                    int v1 = __builtin_amdgcn_ds_bpermute(idx, ws[2 * ks + 1][hp & 1]);
                    wt[ks][hp] = ghigh ? v1 : v0;
                }
        }

        // PV
#pragma unroll
        for (int ks = 0; ks < 2; ++ks) {
            bf16x8 pa0 = *(const bf16x8*)&wt0[ks][0];
            bf16x8 pa1 = *(const bf16x8*)&wt1[ks][0];
#pragma unroll
            for (int dt = 0; dt < 4; ++dt) {
                int d = dt * 16 + lr;
                int xv = (ks * 4 + g) ^ (lr & 7) ^ (dt * 2 + (lr >> 3));
                bf16x8 vf = *(const bf16x8*)&Vt[d * 64 + xv * 8];
                if (act0) O[0][dt] = __builtin_amdgcn_mfma_f32_16x16x32_bf16(pa0, vf, O[0][dt], 0, 0, 0);
                if (act1) O[1][dt] = __builtin_amdgcn_mfma_f32_16x16x32_bf16(pa1, vf, O[1][dt], 0, 0, 0);
            }
        }
    }

    // epilogue: normalize by l and store
#pragma unroll
    for (int sub = 0; sub < 2; ++sub) {
        int lv = __builtin_bit_cast(int, l_[sub]);
#pragma unroll
        for (int r = 0; r < 4; ++r) {
            float lval = __builtin_bit_cast(float, __builtin_amdgcn_ds_bpermute(idxA[r], lv));
            float inv = __builtin_amdgcn_rcpf(lval);
            int q = q0w + sub * 16 + g * 4 + r;
#pragma unroll
            for (int dt = 0; dt < 4; ++dt)
                y[(size_t)(b * 2048 + q) * 1024 + h * 64 + dt * 16 + lr] =
                    f2bf(O[sub][dt][r] * inv);
        }
    }
}

// ---------------- residual + layernorm: out = base + LN(delta)*g+b ----------------
template <int WRITE_BF>
__global__ __launch_bounds__(256) void ln_kernel(const float* __restrict__ base,
                                                 const float* __restrict__ delta,
                                                 const float* __restrict__ gw,
                                                 const float* __restrict__ bw,
                                                 float* __restrict__ outf,
                                                 unsigned short* __restrict__ outb) {
    const int row = blockIdx.x;
    const int tid = threadIdx.x;
    const float* d = delta + (size_t)row * 1024;
    const float* bs = base + (size_t)row * 1024;
    float4 x = *(const float4*)&d[tid * 4];
    float s = x.x + x.y + x.z + x.w;
    float s2 = x.x * x.x + x.y * x.y + x.z * x.z + x.w * x.w;
#pragma unroll
    for (int off = 1; off < 64; off <<= 1) {
        s += __shfl_xor(s, off);
        s2 += __shfl_xor(s2, off);
    }
    __shared__ float red[8];
    if ((tid & 63) == 0) {
        red[tid >> 6] = s;
        red[4 + (tid >> 6)] = s2;
    }
    __syncthreads();
    s = red[0] + red[1] + red[2] + red[3];
    s2 = red[4] + red[5] + red[6] + red[7];
    float mu = s * (1.f / 1024.f);
    float var = s2 * (1.f / 1024.f) - mu * mu;
    float rsig = rsqrtf(var + 1e-5f);
    float4 bb = *(const float4*)&bs[tid * 4];
    float4 gv = *(const float4*)&gw[tid * 4];
    float4 bv = *(const float4*)&bw[tid * 4];
    float4 o;
    o.x = bb.x + (x.x - mu) * rsig * gv.x + bv.x;
    o.y = bb.y + (x.y - mu) * rsig * gv.y + bv.y;
    o.z = bb.z + (x.z - mu) * rsig * gv.z + bv.z;
    o.w = bb.w + (x.w - mu) * rsig * gv.w + bv.w;
    *(float4*)&outf[(size_t)row * 1024 + tid * 4] = o;
    if (WRITE_BF) {
        unsigned short* ob = outb + (size_t)row * 1024 + tid * 4;
        ob[0] = f2bf(o.x);
        ob[1] = f2bf(o.y);
        ob[2] = f2bf(o.z);
        ob[3] = f2bf(o.w);
    }
}

extern "C" void kernel_launch(void* const* d_in, const int* in_sizes, int n_in,
                              void* d_out, int out_size, void* d_ws, size_t ws_size,
                              hipStream_t stream) {
    const float* x = (const float*)d_in[0];
    const float* w_qkv = (const float*)d_in[1];
    const float* b_qkv = (const float*)d_in[2];
    const float* w_out = (const float*)d_in[3];
    const float* b_out = (const float*)d_in[4];
    const float* w1 = (const float*)d_in[5];
    const float* b1 = (const float*)d_in[6];
    const float* w2 = (const float*)d_in[7];
    const float* b2 = (const float*)d_in[8];
    const float* g1 = (const float*)d_in[9];
    const float* be1 = (const float*)d_in[10];
    const float* g2 = (const float*)d_in[11];
    const float* be2 = (const float*)d_in[12];

    const size_t MB = 1ull << 20;
    if (ws_size < 184 * MB) return;
    char* ws = (char*)d_ws;
    unsigned short* xb    = (unsigned short*)(ws + 0);         // 16MB
    unsigned short* wqkvt = (unsigned short*)(ws + 16 * MB);   // 6MB
    unsigned short* qkvb  = (unsigned short*)(ws + 22 * MB);   // 48MB
    unsigned short* hb    = (unsigned short*)(ws + 0);         // 64MB (reuse)
    unsigned short* woutt = (unsigned short*)(ws + 70 * MB);   // 2MB
    unsigned short* yb    = (unsigned short*)(ws + 72 * MB);   // 16MB
    float*          attnp = (float*)(ws + 88 * MB);            // 32MB
    float*          ff    = (float*)(ws + 88 * MB);            // 32MB (reuse)
    float*          x2f   = (float*)(ws + 120 * MB);           // 32MB
    unsigned short* x2b   = (unsigned short*)(ws + 152 * MB);  // 16MB
    unsigned short* w1t   = (unsigned short*)(ws + 168 * MB);  // 8MB
    unsigned short* w2t   = (unsigned short*)(ws + 176 * MB);  // 8MB

    // prep
    cvtbf_kernel<<<8192, 256, 0, stream>>>(x, xb);
    transpose_cvt_kernel<<<dim3(96, 32), dim3(32, 8), 0, stream>>>(w_qkv, wqkvt, 1024, 3072);
    transpose_cvt_kernel<<<dim3(32, 32), dim3(32, 8), 0, stream>>>(w_out, woutt, 1024, 1024);
    transpose_cvt_kernel<<<dim3(128, 32), dim3(32, 8), 0, stream>>>(w1, w1t, 1024, 4096);
    transpose_cvt_kernel<<<dim3(32, 128), dim3(32, 8), 0, stream>>>(w2, w2t, 4096, 1024);
    // qkv = x @ w_qkv + b_qkv  (bf16 out)
    gemm_kernel<0, 1><<<dim3(24, 64), 256, 0, stream>>>(xb, wqkvt, b_qkv, qkvb, 8192, 3072, 1024);
    // attention
    attn_kernel<<<dim3(16, 16, 4), 256, 0, stream>>>(qkvb, yb);
    // out proj (f32 out)
    gemm_kernel<0, 0><<<dim3(8, 64), 256, 0, stream>>>(yb, woutt, b_out, attnp, 8192, 1024, 1024);
    // x2 = x + LN(attnp)
    ln_kernel<1><<<8192, 256, 0, stream>>>(x, attnp, g1, be1, x2f, x2b);
    // h = gelu(x2 @ w1 + b1) (bf16 out)
    gemm_kernel<1, 1><<<dim3(32, 64), 256, 0, stream>>>(x2b, w1t, b1, hb, 8192, 4096, 1024);
    // f = h @ w2 + b2 (f32 out)
    gemm_kernel<0, 0><<<dim3(8, 64), 256, 0, stream>>>(hb, w2t, b2, ff, 8192, 1024, 4096);
    // out = x2 + LN(f)
    ln_kernel<0><<<8192, 256, 0, stream>>>(x2f, ff, g2, be2, (float*)d_out, nullptr);
}

// Round 3
// 671.372 us; speedup vs baseline: 1.2247x; 1.1405x over previous
//
#include <hip/hip_runtime.h>
#include <hip/hip_bf16.h>

typedef unsigned short ushort_t;
using bf16x8 = __attribute__((ext_vector_type(8))) short;
using f32x4  = __attribute__((ext_vector_type(4))) float;

#define DEV __device__ __forceinline__

DEV unsigned short f2bf(float f) {
    unsigned int u = __builtin_bit_cast(unsigned int, f);
    u = (u + 0x7fffu + ((u >> 16) & 1u)) >> 16;
    return (unsigned short)u;
}

DEV int cvtpk_bf16(float lo, float hi) {
    int r;
    asm("v_cvt_pk_bf16_f32 %0, %1, %2" : "=v"(r) : "v"(lo), "v"(hi));
    return r;
}

DEV void gload16(const unsigned short* g, unsigned short* l) {
    __builtin_amdgcn_global_load_lds(
        (const __attribute__((address_space(1))) void*)g,
        (__attribute__((address_space(3))) void*)l, 16, 0, 0);
}

// ---------------- f32 -> bf16 convert ----------------
__global__ __launch_bounds__(256) void cvtbf_kernel(const float* __restrict__ in,
                                                    unsigned short* __restrict__ out) {
    int i = (blockIdx.x * 256 + threadIdx.x) * 4;
    float4 v = *(const float4*)&in[i];
    out[i + 0] = f2bf(v.x);
    out[i + 1] = f2bf(v.y);
    out[i + 2] = f2bf(v.z);
    out[i + 3] = f2bf(v.w);
}

// ---------------- transpose + convert: in[R,C] f32 -> out[C,R] bf16 ----------------
__global__ __launch_bounds__(256) void transpose_cvt_kernel(const float* __restrict__ in,
                                                            unsigned short* __restrict__ out,
                                                            int R, int C) {
    __shared__ float t[32][33];
    int tx = threadIdx.x, ty = threadIdx.y;
    int c0 = blockIdx.x * 32, r0 = blockIdx.y * 32;
#pragma unroll
    for (int i = 0; i < 4; ++i)
        t[ty + i * 8][tx] = in[(size_t)(r0 + ty + i * 8) * C + c0 + tx];
    __syncthreads();
#pragma unroll
    for (int i = 0; i < 4; ++i)
        out[(size_t)(c0 + ty + i * 8) * R + r0 + tx] = f2bf(t[tx][ty + i * 8]);
}

// ---------------- V transpose: qkvb V-part -> vtg[bh][64][2048] bf16 ----------------
__global__ __launch_bounds__(256) void vtrans_kernel(const unsigned short* __restrict__ qkvb,
                                                     unsigned short* __restrict__ vtg) {
    __shared__ unsigned short t[64 * 66];
    const int tid = threadIdx.x;
    const int t0 = blockIdx.x * 64;
    const int bh = blockIdx.y;
    const int b = bh >> 4, h = bh & 15;
    const unsigned short* src = qkvb + (size_t)(b * 2048 + t0) * 3072 + 2048 + h * 64;
#pragma unroll
    for (int c = 0; c < 2; ++c) {
        int cid = c * 256 + tid;
        int row = cid >> 3, cc = cid & 7;
        *(int4*)&t[row * 66 + cc * 8] = *(const int4*)&src[(size_t)row * 3072 + cc * 8];
    }
    __syncthreads();
    unsigned short* dst = vtg + (size_t)bh * 64 * 2048 + t0;
#pragma unroll
    for (int c = 0; c < 2; ++c) {
        int cid = c * 256 + tid;
        int d = cid >> 3, cc2 = cid & 7;
        bf16x8 v;
#pragma unroll
        for (int j = 0; j < 8; ++j) v[j] = (short)t[(cc2 * 8 + j) * 66 + d];
        *(bf16x8*)&dst[(size_t)d * 2048 + cc2 * 8] = v;
    }
}

// ---------------- GEMM: A[M,K]bf16 @ Bt[N,K]bf16^T + bias -> out ----------------
template <int ACT, int OBF>
__global__ __launch_bounds__(256) void gemm_kernel(const unsigned short* __restrict__ A,
                                                   const unsigned short* __restrict__ Bt,
                                                   const float* __restrict__ bias,
                                                   void* __restrict__ out,
                                                   int M, int N, int K) {
    __shared__ unsigned short lA[128 * 64];
    __shared__ unsigned short lB[128 * 64];
    const int tid = threadIdx.x;
    const int lane = tid & 63, w = tid >> 6;
    const int wm = w >> 1, wn = w & 1;
    const int g = lane >> 4, lr = lane & 15;
    const int m0 = blockIdx.y * 128, n0 = blockIdx.x * 128;

    f32x4 acc[4][4] = {};
    const int nkt = K >> 6;
    for (int kt = 0; kt < nkt; ++kt) {
        __syncthreads();
        const int k0 = kt << 6;
#pragma unroll
        for (int i = 0; i < 4; ++i) {
            int ci = i * 256 + w * 64 + lane;  // 0..1023
            int row = ci & 127, kb = ci >> 7;
            gload16(&A[(size_t)(m0 + row) * K + k0 + kb * 8], &lA[(size_t)(i * 256 + w * 64) * 8]);
            gload16(&Bt[(size_t)(n0 + row) * K + k0 + kb * 8], &lB[(size_t)(i * 256 + w * 64) * 8]);
        }
        __syncthreads();
#pragma unroll
        for (int ks = 0; ks < 2; ++ks) {
            bf16x8 af[4], bfr[4];
#pragma unroll
            for (int mf = 0; mf < 4; ++mf) {
                int ci = (ks * 4 + g) * 128 + wm * 64 + mf * 16 + lr;
                af[mf] = *(const bf16x8*)&lA[ci * 8];
            }
#pragma unroll
            for (int nf = 0; nf < 4; ++nf) {
                int ci = (ks * 4 + g) * 128 + wn * 64 + nf * 16 + lr;
                bfr[nf] = *(const bf16x8*)&lB[ci * 8];
            }
#pragma unroll
            for (int mf = 0; mf < 4; ++mf)
#pragma unroll
                for (int nf = 0; nf < 4; ++nf)
                    acc[mf][nf] = __builtin_amdgcn_mfma_f32_16x16x32_bf16(af[mf], bfr[nf],
                                                                          acc[mf][nf], 0, 0, 0);
        }
    }
#pragma unroll
    for (int mf = 0; mf < 4; ++mf) {
#pragma unroll
        for (int nf = 0; nf < 4; ++nf) {
            int col = n0 + wn * 64 + nf * 16 + lr;
            float bv = bias[col];
#pragma unroll
            for (int r = 0; r < 4; ++r) {
                int row = m0 + wm * 64 + mf * 16 + g * 4 + r;
                float v = acc[mf][nf][r] + bv;
                if (ACT == 1) v = 0.5f * v * (1.0f + erff(v * 0.70710678118f));
                if (OBF)
                    ((unsigned short*)out)[(size_t)row * N + col] = f2bf(v);
                else
                    ((float*)out)[(size_t)row * N + col] = v;
            }
        }
    }
}

// ---------------- flash attention v3 ----------------
// Block x=p handles q-tiles J=15-p then J=p (uniform 36 tile-units/block).
// K and V^T staged via global_load_lds (source-swizzled, linear dest),
// double-buffered LDS, one barrier per tile with counted-vmcnt prefetch.
__global__ __launch_bounds__(256) void attn_kernel(const unsigned short* __restrict__ qkv,
                                                   const unsigned short* __restrict__ vtg,
                                                   unsigned short* __restrict__ y) {
    __shared__ unsigned short Kl[2][4096];
    __shared__ unsigned short Vl[2][4096];
    const int tid = threadIdx.x, lane = tid & 63, w = tid >> 6;
    const int g = lane >> 4, lr = lane & 15;
    const int p = blockIdx.x, h = blockIdx.y, b = blockIdx.z;
    const int bh = b * 16 + h;
    const size_t rs3 = 3072;
    const unsigned short* qbase = qkv + (size_t)b * 2048 * rs3 + h * 64;
    const unsigned short* kbase = qbase + 1024;
    const unsigned short* vbase = vtg + (size_t)bh * 64 * 2048;

    // per-lane staging source offsets (XOR swizzle folded into the GLOBAL address;
    // LDS dest stays linear as global_load_lds requires)
    int ksoff[2], vsoff[2], ldoff[2];
#pragma unroll
    for (int c = 0; c < 2; ++c) {
        int row = w * 16 + c * 8 + (lane >> 3);
        int ccs = (lane & 7) ^ (row & 7) ^ (row >> 3);
        ksoff[c] = row * 3072 + ccs * 8;
        vsoff[c] = row * 2048 + ccs * 8;
        ldoff[c] = (w * 16 + c * 8) * 64;
    }

    // bpermute byte-index vectors
    const int idxP0 = 4 * (32 * (g & 1) + lr);
    const int idxP1 = idxP0 + 64;
    int idxA[4];
#pragma unroll
    for (int r = 0; r < 4; ++r) idxA[r] = 4 * (g * 20 + r);
    const bool ghigh = (g >> 1) != 0;
    const float qscale = 0.125f * 1.44269504089f;

    auto process = [&](int J) {
        const int q0w = J * 128 + w * 32;
        const int ktend = 2 * J + 2;
        // prologue: stage tile 0 into buf 0
#pragma unroll
        for (int c = 0; c < 2; ++c) {
            gload16(&kbase[ksoff[c]], &Kl[0][ldoff[c]]);
            gload16(&vbase[vsoff[c]], &Vl[0][ldoff[c]]);
        }
        // Q fragments, pre-scaled (exp2-domain softmax)
        int qf[2][2][4];
#pragma unroll
        for (int sub = 0; sub < 2; ++sub)
#pragma unroll
            for (int f = 0; f < 2; ++f) {
                int4 v = *(const int4*)&qbase[(size_t)(q0w + sub * 16 + lr) * rs3 + f * 32 + g * 8];
                int vv[4] = {v.x, v.y, v.z, v.w};
#pragma unroll
                for (int i = 0; i < 4; ++i) {
                    unsigned int u = (unsigned int)vv[i];
                    float lo = __builtin_bit_cast(float, u << 16) * qscale;
                    float hi = __builtin_bit_cast(float, u & 0xffff0000u) * qscale;
                    qf[sub][f][i] = cvtpk_bf16(lo, hi);
                }
            }

        f32x4 O[2][4] = {};
        float m_[2] = {-3.0e38f, -3.0e38f}, l_[2] = {0.f, 0.f};

        int buf = 0;
        for (int kt = 0; kt < ktend; ++kt) {
            asm volatile("s_waitcnt vmcnt(0)" ::: "memory");
            __builtin_amdgcn_s_barrier();
            __builtin_amdgcn_sched_barrier(0);
            if (kt + 1 < ktend) {
#pragma unroll
                for (int c = 0; c < 2; ++c) {
                    gload16(&kbase[(size_t)(kt + 1) * 64 * 3072 + ksoff[c]], &Kl[buf ^ 1][ldoff[c]]);
                    gload16(&vbase[vsoff[c] + (kt + 1) * 64], &Vl[buf ^ 1][ldoff[c]]);
                }
            }
            const unsigned short* Kc = Kl[buf];
            const unsigned short* Vc = Vl[buf];

            const bool act0 = (kt * 64) <= (q0w + 15);
            const bool act1 = (kt * 64) <= (q0w + 31);

            // QK^T swapped: S^T tiles
            f32x4 s0[4], s1[4];
#pragma unroll
            for (int st = 0; st < 4; ++st) {
                int rbase = (st * 16 + lr) * 64;
                int sw = (lr & 7) ^ (st * 2 + (lr >> 3));
                bf16x8 kf0 = *(const bf16x8*)&Kc[rbase + ((g ^ sw) * 8)];
                bf16x8 kf1 = *(const bf16x8*)&Kc[rbase + (((4 + g) ^ sw) * 8)];
                if (act0) {
                    f32x4 a = {};
                    a = __builtin_amdgcn_mfma_f32_16x16x32_bf16(kf0, *(const bf16x8*)&qf[0][0], a, 0, 0, 0);
                    a = __builtin_amdgcn_mfma_f32_16x16x32_bf16(kf1, *(const bf16x8*)&qf[0][1], a, 0, 0, 0);
                    s0[st] = a;
                }
                if (act1) {
                    f32x4 a = {};
                    a = __builtin_amdgcn_mfma_f32_16x16x32_bf16(kf0, *(const bf16x8*)&qf[1][0], a, 0, 0, 0);
                    a = __builtin_amdgcn_mfma_f32_16x16x32_bf16(kf1, *(const bf16x8*)&qf[1][1], a, 0, 0, 0);
                    s1[st] = a;
                }
            }

            int wt0[2][4], wt1[2][4];
#pragma unroll
            for (int sub = 0; sub < 2; ++sub) {
                if (sub == 0 && !act0) continue;
                if (sub == 1 && !act1) continue;
                f32x4* s = (sub == 0) ? s0 : s1;
                const int qmin = q0w + sub * 16;
                if (kt * 64 + 63 > qmin) {  // diagonal tile: causal mask
                    int qv = qmin + lr;
#pragma unroll
                    for (int st = 0; st < 4; ++st) {
                        int keyb = kt * 64 + st * 16 + g * 4;
#pragma unroll
                        for (int r = 0; r < 4; ++r)
                            if (keyb + r > qv) s[st][r] = -3.0e38f;
                    }
                }
                float mx = fmaxf(fmaxf(s[0][0], s[0][1]), fmaxf(s[0][2], s[0][3]));
#pragma unroll
                for (int st = 1; st < 4; ++st)
                    mx = fmaxf(mx, fmaxf(fmaxf(s[st][0], s[st][1]), fmaxf(s[st][2], s[st][3])));
                mx = fmaxf(mx, __shfl_xor(mx, 16));
                mx = fmaxf(mx, __shfl_xor(mx, 32));
                float mold = m_[sub];
                float mnew = fmaxf(mold, mx);
                float alpha = __builtin_amdgcn_exp2f(mold - mnew);
                m_[sub] = mnew;
                float rs = 0.f;
#pragma unroll
                for (int st = 0; st < 4; ++st)
#pragma unroll
                    for (int r = 0; r < 4; ++r) {
                        float pp = __builtin_amdgcn_exp2f(s[st][r] - mnew);
                        s[st][r] = pp;
                        rs += pp;
                    }
                rs += __shfl_xor(rs, 16);
                rs += __shfl_xor(rs, 32);
                l_[sub] = l_[sub] * alpha + rs;
                int av = __builtin_bit_cast(int, alpha);
                f32x4* Os = O[sub];
#pragma unroll
                for (int r = 0; r < 4; ++r) {
                    float ar = __builtin_bit_cast(float, __builtin_amdgcn_ds_bpermute(idxA[r], av));
#pragma unroll
                    for (int dt = 0; dt < 4; ++dt) Os[dt][r] *= ar;
                }
                int ws_[4][2];
#pragma unroll
                for (int st = 0; st < 4; ++st) {
                    ws_[st][0] = cvtpk_bf16(s[st][0], s[st][1]);
                    ws_[st][1] = cvtpk_bf16(s[st][2], s[st][3]);
                }
                int(*wt)[4] = (sub == 0) ? wt0 : wt1;
#pragma unroll
                for (int ks = 0; ks < 2; ++ks)
#pragma unroll
                    for (int hp = 0; hp < 4; ++hp) {
                        int idx = (hp < 2) ? idxP0 : idxP1;
                        int v0 = __builtin_amdgcn_ds_bpermute(idx, ws_[2 * ks][hp & 1]);
                        int v1 = __builtin_amdgcn_ds_bpermute(idx, ws_[2 * ks + 1][hp & 1]);
                        wt[ks][hp] = ghigh ? v1 : v0;
                    }
            }

            // PV
#pragma unroll
            for (int ks = 0; ks < 2; ++ks) {
                bf16x8 pa0 = *(const bf16x8*)&wt0[ks][0];
                bf16x8 pa1 = *(const bf16x8*)&wt1[ks][0];
#pragma unroll
                for (int dt = 0; dt < 4; ++dt) {
                    int d = dt * 16 + lr;
                    int xv = (ks * 4 + g) ^ (lr & 7) ^ (dt * 2 + (lr >> 3));
                    bf16x8 vf = *(const bf16x8*)&Vc[d * 64 + xv * 8];
                    if (act0) O[0][dt] = __builtin_amdgcn_mfma_f32_16x16x32_bf16(pa0, vf, O[0][dt], 0, 0, 0);
                    if (act1) O[1][dt] = __builtin_amdgcn_mfma_f32_16x16x32_bf16(pa1, vf, O[1][dt], 0, 0, 0);
                }
            }
            buf ^= 1;
        }

        // epilogue: normalize by l and store
#pragma unroll
        for (int sub = 0; sub < 2; ++sub) {
            int lv = __builtin_bit_cast(int, l_[sub]);
#pragma unroll
            for (int r = 0; r < 4; ++r) {
                float lval = __builtin_bit_cast(float, __builtin_amdgcn_ds_bpermute(idxA[r], lv));
                float inv = __builtin_amdgcn_rcpf(lval);
                int q = q0w + sub * 16 + g * 4 + r;
#pragma unroll
                for (int dt = 0; dt < 4; ++dt)
                    y[(size_t)(b * 2048 + q) * 1024 + h * 64 + dt * 16 + lr] =
                        f2bf(O[sub][dt][r] * inv);
            }
        }
    };

    process(15 - p);
    __syncthreads();
    process(p);
}

// ---------------- residual + layernorm: out = base + LN(delta)*g+b ----------------
template <int WRITE_BF>
__global__ __launch_bounds__(256) void ln_kernel(const float* __restrict__ base,
                                                 const float* __restrict__ delta,
                                                 const float* __restrict__ gw,
                                                 const float* __restrict__ bw,
                                                 float* __restrict__ outf,
                                                 unsigned short* __restrict__ outb) {
    const int row = blockIdx.x;
    const int tid = threadIdx.x;
    const float* d = delta + (size_t)row * 1024;
    const float* bs = base + (size_t)row * 1024;
    float4 x = *(const float4*)&d[tid * 4];
    float s = x.x + x.y + x.z + x.w;
    float s2 = x.x * x.x + x.y * x.y + x.z * x.z + x.w * x.w;
#pragma unroll
    for (int off = 1; off < 64; off <<= 1) {
        s += __shfl_xor(s, off);
        s2 += __shfl_xor(s2, off);
    }
    __shared__ float red[8];
    if ((tid & 63) == 0) {
        red[tid >> 6] = s;
        red[4 + (tid >> 6)] = s2;
    }
    __syncthreads();
    s = red[0] + red[1] + red[2] + red[3];
    s2 = red[4] + red[5] + red[6] + red[7];
    float mu = s * (1.f / 1024.f);
    float var = s2 * (1.f / 1024.f) - mu * mu;
    float rsig = rsqrtf(var + 1e-5f);
    float4 bb = *(const float4*)&bs[tid * 4];
    float4 gv = *(const float4*)&gw[tid * 4];
    float4 bv = *(const float4*)&bw[tid * 4];
    float4 o;
    o.x = bb.x + (x.x - mu) * rsig * gv.x + bv.x;
    o.y = bb.y + (x.y - mu) * rsig * gv.y + bv.y;
    o.z = bb.z + (x.z - mu) * rsig * gv.z + bv.z;
    o.w = bb.w + (x.w - mu) * rsig * gv.w + bv.w;
    *(float4*)&outf[(size_t)row * 1024 + tid * 4] = o;
    if (WRITE_BF) {
        unsigned short* ob = outb + (size_t)row * 1024 + tid * 4;
        ob[0] = f2bf(o.x);
        ob[1] = f2bf(o.y);
        ob[2] = f2bf(o.z);
        ob[3] = f2bf(o.w);
    }
}

extern "C" void kernel_launch(void* const* d_in, const int* in_sizes, int n_in,
                              void* d_out, int out_size, void* d_ws, size_t ws_size,
                              hipStream_t stream) {
    const float* x = (const float*)d_in[0];
    const float* w_qkv = (const float*)d_in[1];
    const float* b_qkv = (const float*)d_in[2];
    const float* w_out = (const float*)d_in[3];
    const float* b_out = (const float*)d_in[4];
    const float* w1 = (const float*)d_in[5];
    const float* b1 = (const float*)d_in[6];
    const float* w2 = (const float*)d_in[7];
    const float* b2 = (const float*)d_in[8];
    const float* g1 = (const float*)d_in[9];
    const float* be1 = (const float*)d_in[10];
    const float* g2 = (const float*)d_in[11];
    const float* be2 = (const float*)d_in[12];

    const size_t MB = 1ull << 20;
    if (ws_size < 184 * MB) return;
    char* ws = (char*)d_ws;
    unsigned short* xb    = (unsigned short*)(ws + 0);         // 16MB (dead after qkv gemm)
    unsigned short* vtg   = (unsigned short*)(ws + 0);         // 16MB (V^T, lives during attn)
    unsigned short* wqkvt = (unsigned short*)(ws + 16 * MB);   // 6MB
    unsigned short* qkvb  = (unsigned short*)(ws + 22 * MB);   // 48MB
    unsigned short* hb    = (unsigned short*)(ws + 0);         // 64MB (reuse, MLP phase)
    unsigned short* woutt = (unsigned short*)(ws + 70 * MB);   // 2MB
    unsigned short* yb    = (unsigned short*)(ws + 72 * MB);   // 16MB
    float*          attnp = (float*)(ws + 88 * MB);            // 32MB
    float*          ff    = (float*)(ws + 88 * MB);            // 32MB (reuse)
    float*          x2f   = (float*)(ws + 120 * MB);           // 32MB
    unsigned short* x2b   = (unsigned short*)(ws + 152 * MB);  // 16MB
    unsigned short* w1t   = (unsigned short*)(ws + 168 * MB);  // 8MB
    unsigned short* w2t   = (unsigned short*)(ws + 176 * MB);  // 8MB

    // prep
    cvtbf_kernel<<<8192, 256, 0, stream>>>(x, xb);
    transpose_cvt_kernel<<<dim3(96, 32), dim3(32, 8), 0, stream>>>(w_qkv, wqkvt, 1024, 3072);
    transpose_cvt_kernel<<<dim3(32, 32), dim3(32, 8), 0, stream>>>(w_out, woutt, 1024, 1024);
    transpose_cvt_kernel<<<dim3(128, 32), dim3(32, 8), 0, stream>>>(w1, w1t, 1024, 4096);
    transpose_cvt_kernel<<<dim3(32, 128), dim3(32, 8), 0, stream>>>(w2, w2t, 4096, 1024);
    // qkv = x @ w_qkv + b_qkv  (bf16 out)
    gemm_kernel<0, 1><<<dim3(24, 64), 256, 0, stream>>>(xb, wqkvt, b_qkv, qkvb, 8192, 3072, 1024);
    // V^T pre-transpose (after qkv gemm; overwrites dead xb region)
    vtrans_kernel<<<dim3(32, 64), 256, 0, stream>>>(qkvb, vtg);
    // attention
    attn_kernel<<<dim3(8, 16, 4), 256, 0, stream>>>(qkvb, vtg, yb);
    // out proj (f32 out)
    gemm_kernel<0, 0><<<dim3(8, 64), 256, 0, stream>>>(yb, woutt, b_out, attnp, 8192, 1024, 1024);
    // x2 = x + LN(attnp)
    ln_kernel<1><<<8192, 256, 0, stream>>>(x, attnp, g1, be1, x2f, x2b);
    // h = gelu(x2 @ w1 + b1) (bf16 out)
    gemm_kernel<1, 1><<<dim3(32, 64), 256, 0, stream>>>(x2b, w1t, b1, hb, 8192, 4096, 1024);
    // f = h @ w2 + b2 (f32 out)
    gemm_kernel<0, 0><<<dim3(8, 64), 256, 0, stream>>>(hb, w2t, b2, ff, 8192, 1024, 4096);
    // out = x2 + LN(f)
    ln_kernel<0><<<8192, 256, 0, stream>>>(x2f, ff, g2, be2, (float*)d_out, nullptr);
}

// Round 4
// 649.403 us; speedup vs baseline: 1.2661x; 1.0338x over previous
//
#include <hip/hip_runtime.h>
#include <hip/hip_bf16.h>

typedef unsigned short ushort_t;
using bf16x8 = __attribute__((ext_vector_type(8))) short;
using f32x4  = __attribute__((ext_vector_type(4))) float;

#define DEV __device__ __forceinline__

DEV unsigned short f2bf(float f) {
    unsigned int u = __builtin_bit_cast(unsigned int, f);
    u = (u + 0x7fffu + ((u >> 16) & 1u)) >> 16;
    return (unsigned short)u;
}

DEV int cvtpk_bf16(float lo, float hi) {
    int r;
    asm("v_cvt_pk_bf16_f32 %0, %1, %2" : "=v"(r) : "v"(lo), "v"(hi));
    return r;
}

DEV void gload16(const unsigned short* g, unsigned short* l) {
    __builtin_amdgcn_global_load_lds(
        (const __attribute__((address_space(1))) void*)g,
        (__attribute__((address_space(3))) void*)l, 16, 0, 0);
}

// tanh-form GELU: v * t/(t+1), t = exp2(2*log2e*u), u = sqrt(2/pi)*(v+0.044715v^3)
DEV float gelu_f(float v) {
    float u = v * (0.79788456f + 0.03567741f * v * v);
    float t = __builtin_amdgcn_exp2f(u * 2.88539008f);
    return v * t * __builtin_amdgcn_rcpf(t + 1.0f);
}

// ---------------- f32 -> bf16 convert ----------------
__global__ __launch_bounds__(256) void cvtbf_kernel(const float* __restrict__ in,
                                                    unsigned short* __restrict__ out) {
    int i = (blockIdx.x * 256 + threadIdx.x) * 4;
    float4 v = *(const float4*)&in[i];
    out[i + 0] = f2bf(v.x);
    out[i + 1] = f2bf(v.y);
    out[i + 2] = f2bf(v.z);
    out[i + 3] = f2bf(v.w);
}

// ---------------- transpose + convert: in[R,C] f32 -> out[C,R] bf16 ----------------
__global__ __launch_bounds__(256) void transpose_cvt_kernel(const float* __restrict__ in,
                                                            unsigned short* __restrict__ out,
                                                            int R, int C) {
    __shared__ float t[32][33];
    int tx = threadIdx.x, ty = threadIdx.y;
    int c0 = blockIdx.x * 32, r0 = blockIdx.y * 32;
#pragma unroll
    for (int i = 0; i < 4; ++i)
        t[ty + i * 8][tx] = in[(size_t)(r0 + ty + i * 8) * C + c0 + tx];
    __syncthreads();
#pragma unroll
    for (int i = 0; i < 4; ++i)
        out[(size_t)(c0 + ty + i * 8) * R + r0 + tx] = f2bf(t[tx][ty + i * 8]);
}

// ---------------- V transpose: qkvb V-part -> vtg[bh][64][2048] bf16 ----------------
__global__ __launch_bounds__(256) void vtrans_kernel(const unsigned short* __restrict__ qkvb,
                                                     unsigned short* __restrict__ vtg) {
    __shared__ unsigned short t[64 * 66];
    const int tid = threadIdx.x;
    const int t0 = blockIdx.x * 64;
    const int bh = blockIdx.y;
    const int b = bh >> 4, h = bh & 15;
    const unsigned short* src = qkvb + (size_t)(b * 2048 + t0) * 3072 + 2048 + h * 64;
#pragma unroll
    for (int c = 0; c < 2; ++c) {
        int cid = c * 256 + tid;
        int row = cid >> 3, cc = cid & 7;
        *(int4*)&t[row * 66 + cc * 8] = *(const int4*)&src[(size_t)row * 3072 + cc * 8];
    }
    __syncthreads();
    unsigned short* dst = vtg + (size_t)bh * 64 * 2048 + t0;
#pragma unroll
    for (int c = 0; c < 2; ++c) {
        int cid = c * 256 + tid;
        int d = cid >> 3, cc2 = cid & 7;
        bf16x8 v;
#pragma unroll
        for (int j = 0; j < 8; ++j) v[j] = (short)t[(cc2 * 8 + j) * 66 + d];
        *(bf16x8*)&dst[(size_t)d * 2048 + cc2 * 8] = v;
    }
}

// ---------------- GEMM 256xBN, BK=64, 8 waves, 4-phase K-tile, deferred vmcnt ------
// A[M,K] bf16, Bt[N,K] bf16 (pre-transposed). Chunked LDS: chunk ci=kb*ROWS+row
// holds X[row][kb*8..+7] (16B) -> conflict-free ds_read_b128 + linear gload_lds dest.
template <int BN, int WM, int WN, int ACT, int OBF>
__global__ __launch_bounds__(512, 2) void gemm256_kernel(
    const unsigned short* __restrict__ A, const unsigned short* __restrict__ Bt,
    const float* __restrict__ bias, void* __restrict__ out,
    int N, int K, int gridMt) {
    constexpr int MF = 16 / WM;        // M frags/wave
    constexpr int NF = BN / (WN * 16); // N frags/wave
    constexpr int ACH = 2048;          // A chunks per K-tile (8 kb * 256 rows)
    constexpr int BCH = BN * 8;
    constexpr int ASTG = ACH / 512;    // 4
    constexpr int BSTG = BCH / 512;    // 4 (BN=256) or 2 (BN=128)
    __shared__ __align__(16) unsigned short lA[2][ACH * 8];
    __shared__ __align__(16) unsigned short lB[2][BCH * 8];
    const int tid = threadIdx.x;
    const int lane = tid & 63, wid = tid >> 6;
    const int g = lane >> 4, lr = lane & 15;
    const int wm = wid / WN, wn = wid % WN;

    // XCD-aware bijective swizzle (grid % 8 == 0), column-major work id
    const int nwg = gridDim.x, cpx = nwg >> 3, bid = blockIdx.x;
    const int wkid = (bid & 7) * cpx + (bid >> 3);
    const int mt = wkid % gridMt, nt = wkid / gridMt;
    const int m0 = mt * 256, n0 = nt * BN;

    auto stageA = [&](int s, int kt, int bb) {
        int ci = s * 512 + tid;
        int row = ci & 255, kb = ci >> 8;
        gload16(&A[(size_t)(m0 + row) * K + kt * 64 + kb * 8],
                &lA[bb][(size_t)(s * 512 + (tid & ~63)) * 8]);
    };
    auto stageB = [&](int s, int kt, int bb) {
        int ci = s * 512 + tid;
        int row = ci & (BN - 1), kb = ci / BN;
        gload16(&Bt[(size_t)(n0 + row) * K + kt * 64 + kb * 8],
                &lB[bb][(size_t)(s * 512 + (tid & ~63)) * 8]);
    };

    f32x4 acc[MF][NF] = {};
    bf16x8 af[MF / 2][2];
    bf16x8 bf[NF][2];

    const int nkt = K >> 6;
    // prologue: stage K-tile 0 into buf 0
#pragma unroll
    for (int s = 0; s < ASTG; ++s) stageA(s, 0, 0);
#pragma unroll
    for (int s = 0; s < BSTG; ++s) stageB(s, 0, 0);

    for (int kt = 0; kt < nkt; ++kt) {
        const int b = kt & 1;
        const int ktn = kt + 1;
        // all outstanding loads at this point are exactly this K-tile's stages
        asm volatile("s_waitcnt vmcnt(0)" ::: "memory");
        __builtin_amdgcn_s_barrier();
        __builtin_amdgcn_sched_barrier(0);
#pragma unroll
        for (int p = 0; p < 4; ++p) {
            const int mh = p >> 1, nh = p & 1;
            // ds_read register subtiles (no re-reads across phases)
            if (p == 0 || p == 2) {
#pragma unroll
                for (int mf2 = 0; mf2 < MF / 2; ++mf2)
#pragma unroll
                    for (int ks = 0; ks < 2; ++ks) {
                        int ci = (ks * 4 + g) * 256 + wm * (256 / WM) +
                                 (mh * (MF / 2) + mf2) * 16 + lr;
                        af[mf2][ks] = *(const bf16x8*)&lA[b][(size_t)ci * 8];
                    }
            }
            if (p < 2) {
#pragma unroll
                for (int nf2 = 0; nf2 < NF / 2; ++nf2)
#pragma unroll
                    for (int ks = 0; ks < 2; ++ks) {
                        int nf = p * (NF / 2) + nf2;
                        int ci = (ks * 4 + g) * BN + wn * (BN / WN) + nf * 16 + lr;
                        bf[nf][ks] = *(const bf16x8*)&lB[b][(size_t)ci * 8];
                    }
            }
            // stage next K-tile (2 gload_lds per phase), stays in flight across barriers
            if (ktn < nkt) {
                stageA(p, ktn, b ^ 1);
                if (BSTG == 4) stageB(p, ktn, b ^ 1);
                else if ((p & 1) == 0) stageB(p >> 1, ktn, b ^ 1);
            }
            __builtin_amdgcn_sched_barrier(0);
            __builtin_amdgcn_s_barrier();
            asm volatile("s_waitcnt lgkmcnt(0)" ::: "memory");
            __builtin_amdgcn_sched_barrier(0);
            __builtin_amdgcn_s_setprio(1);
#pragma unroll
            for (int ks = 0; ks < 2; ++ks)
#pragma unroll
                for (int mf2 = 0; mf2 < MF / 2; ++mf2)
#pragma unroll
                    for (int nf2 = 0; nf2 < NF / 2; ++nf2) {
                        int mf = mh * (MF / 2) + mf2, nf = nh * (NF / 2) + nf2;
                        acc[mf][nf] = __builtin_amdgcn_mfma_f32_16x16x32_bf16(
                            af[mf2][ks], bf[nf][ks], acc[mf][nf], 0, 0, 0);
                    }
            __builtin_amdgcn_s_setprio(0);
            __builtin_amdgcn_sched_barrier(0);
            __builtin_amdgcn_s_barrier();
        }
    }

    // epilogue: bias (+GELU) and store
#pragma unroll
    for (int mf = 0; mf < MF; ++mf) {
#pragma unroll
        for (int nf = 0; nf < NF; ++nf) {
            int col = n0 + wn * (BN / WN) + nf * 16 + lr;
            float bv = bias[col];
#pragma unroll
            for (int r = 0; r < 4; ++r) {
                int row = m0 + wm * (256 / WM) + mf * 16 + g * 4 + r;
                float v = acc[mf][nf][r] + bv;
                if (ACT == 1) v = gelu_f(v);
                if (OBF)
                    ((unsigned short*)out)[(size_t)row * N + col] = f2bf(v);
                else
                    ((float*)out)[(size_t)row * N + col] = v;
            }
        }
    }
}

// ---------------- flash attention v3 ----------------
__global__ __launch_bounds__(256) void attn_kernel(const unsigned short* __restrict__ qkv,
                                                   const unsigned short* __restrict__ vtg,
                                                   unsigned short* __restrict__ y) {
    __shared__ unsigned short Kl[2][4096];
    __shared__ unsigned short Vl[2][4096];
    const int tid = threadIdx.x, lane = tid & 63, w = tid >> 6;
    const int g = lane >> 4, lr = lane & 15;
    const int p = blockIdx.x, h = blockIdx.y, b = blockIdx.z;
    const int bh = b * 16 + h;
    const size_t rs3 = 3072;
    const unsigned short* qbase = qkv + (size_t)b * 2048 * rs3 + h * 64;
    const unsigned short* kbase = qbase + 1024;
    const unsigned short* vbase = vtg + (size_t)bh * 64 * 2048;

    int ksoff[2], vsoff[2], ldoff[2];
#pragma unroll
    for (int c = 0; c < 2; ++c) {
        int row = w * 16 + c * 8 + (lane >> 3);
        int ccs = (lane & 7) ^ (row & 7) ^ (row >> 3);
        ksoff[c] = row * 3072 + ccs * 8;
        vsoff[c] = row * 2048 + ccs * 8;
        ldoff[c] = (w * 16 + c * 8) * 64;
    }

    const int idxP0 = 4 * (32 * (g & 1) + lr);
    const int idxP1 = idxP0 + 64;
    int idxA[4];
#pragma unroll
    for (int r = 0; r < 4; ++r) idxA[r] = 4 * (g * 20 + r);
    const bool ghigh = (g >> 1) != 0;
    const float qscale = 0.125f * 1.44269504089f;

    auto process = [&](int J) {
        const int q0w = J * 128 + w * 32;
        const int ktend = 2 * J + 2;
#pragma unroll
        for (int c = 0; c < 2; ++c) {
            gload16(&kbase[ksoff[c]], &Kl[0][ldoff[c]]);
            gload16(&vbase[vsoff[c]], &Vl[0][ldoff[c]]);
        }
        int qf[2][2][4];
#pragma unroll
        for (int sub = 0; sub < 2; ++sub)
#pragma unroll
            for (int f = 0; f < 2; ++f) {
                int4 v = *(const int4*)&qbase[(size_t)(q0w + sub * 16 + lr) * rs3 + f * 32 + g * 8];
                int vv[4] = {v.x, v.y, v.z, v.w};
#pragma unroll
                for (int i = 0; i < 4; ++i) {
                    unsigned int u = (unsigned int)vv[i];
                    float lo = __builtin_bit_cast(float, u << 16) * qscale;
                    float hi = __builtin_bit_cast(float, u & 0xffff0000u) * qscale;
                    qf[sub][f][i] = cvtpk_bf16(lo, hi);
                }
            }

        f32x4 O[2][4] = {};
        float m_[2] = {-3.0e38f, -3.0e38f}, l_[2] = {0.f, 0.f};

        int buf = 0;
        for (int kt = 0; kt < ktend; ++kt) {
            asm volatile("s_waitcnt vmcnt(0)" ::: "memory");
            __builtin_amdgcn_s_barrier();
            __builtin_amdgcn_sched_barrier(0);
            if (kt + 1 < ktend) {
#pragma unroll
                for (int c = 0; c < 2; ++c) {
                    gload16(&kbase[(size_t)(kt + 1) * 64 * 3072 + ksoff[c]], &Kl[buf ^ 1][ldoff[c]]);
                    gload16(&vbase[vsoff[c] + (kt + 1) * 64], &Vl[buf ^ 1][ldoff[c]]);
                }
            }
            const unsigned short* Kc = Kl[buf];
            const unsigned short* Vc = Vl[buf];

            const bool act0 = (kt * 64) <= (q0w + 15);
            const bool act1 = (kt * 64) <= (q0w + 31);

            f32x4 s0[4], s1[4];
#pragma unroll
            for (int st = 0; st < 4; ++st) {
                int rbase = (st * 16 + lr) * 64;
                int sw = (lr & 7) ^ (st * 2 + (lr >> 3));
                bf16x8 kf0 = *(const bf16x8*)&Kc[rbase + ((g ^ sw) * 8)];
                bf16x8 kf1 = *(const bf16x8*)&Kc[rbase + (((4 + g) ^ sw) * 8)];
                if (act0) {
                    f32x4 a = {};
                    a = __builtin_amdgcn_mfma_f32_16x16x32_bf16(kf0, *(const bf16x8*)&qf[0][0], a, 0, 0, 0);
                    a = __builtin_amdgcn_mfma_f32_16x16x32_bf16(kf1, *(const bf16x8*)&qf[0][1], a, 0, 0, 0);
                    s0[st] = a;
                }
                if (act1) {
                    f32x4 a = {};
                    a = __builtin_amdgcn_mfma_f32_16x16x32_bf16(kf0, *(const bf16x8*)&qf[1][0], a, 0, 0, 0);
                    a = __builtin_amdgcn_mfma_f32_16x16x32_bf16(kf1, *(const bf16x8*)&qf[1][1], a, 0, 0, 0);
                    s1[st] = a;
                }
            }

            int wt0[2][4], wt1[2][4];
#pragma unroll
            for (int sub = 0; sub < 2; ++sub) {
                if (sub == 0 && !act0) continue;
                if (sub == 1 && !act1) continue;
                f32x4* s = (sub == 0) ? s0 : s1;
                const int qmin = q0w + sub * 16;
                if (kt * 64 + 63 > qmin) {
                    int qv = qmin + lr;
#pragma unroll
                    for (int st = 0; st < 4; ++st) {
                        int keyb = kt * 64 + st * 16 + g * 4;
#pragma unroll
                        for (int r = 0; r < 4; ++r)
                            if (keyb + r > qv) s[st][r] = -3.0e38f;
                    }
                }
                float mx = fmaxf(fmaxf(s[0][0], s[0][1]), fmaxf(s[0][2], s[0][3]));
#pragma unroll
                for (int st = 1; st < 4; ++st)
                    mx = fmaxf(mx, fmaxf(fmaxf(s[st][0], s[st][1]), fmaxf(s[st][2], s[st][3])));
                mx = fmaxf(mx, __shfl_xor(mx, 16));
                mx = fmaxf(mx, __shfl_xor(mx, 32));
                float mold = m_[sub];
                float mnew = fmaxf(mold, mx);
                float alpha = __builtin_amdgcn_exp2f(mold - mnew);
                m_[sub] = mnew;
                float rs = 0.f;
#pragma unroll
                for (int st = 0; st < 4; ++st)
#pragma unroll
                    for (int r = 0; r < 4; ++r) {
                        float pp = __builtin_amdgcn_exp2f(s[st][r] - mnew);
                        s[st][r] = pp;
                        rs += pp;
                    }
                rs += __shfl_xor(rs, 16);
                rs += __shfl_xor(rs, 32);
                l_[sub] = l_[sub] * alpha + rs;
                int av = __builtin_bit_cast(int, alpha);
                f32x4* Os = O[sub];
#pragma unroll
                for (int r = 0; r < 4; ++r) {
                    float ar = __builtin_bit_cast(float, __builtin_amdgcn_ds_bpermute(idxA[r], av));
#pragma unroll
                    for (int dt = 0; dt < 4; ++dt) Os[dt][r] *= ar;
                }
                int ws_[4][2];
#pragma unroll
                for (int st = 0; st < 4; ++st) {
                    ws_[st][0] = cvtpk_bf16(s[st][0], s[st][1]);
                    ws_[st][1] = cvtpk_bf16(s[st][2], s[st][3]);
                }
                int(*wt)[4] = (sub == 0) ? wt0 : wt1;
#pragma unroll
                for (int ks = 0; ks < 2; ++ks)
#pragma unroll
                    for (int hp = 0; hp < 4; ++hp) {
                        int idx = (hp < 2) ? idxP0 : idxP1;
                        int v0 = __builtin_amdgcn_ds_bpermute(idx, ws_[2 * ks][hp & 1]);
                        int v1 = __builtin_amdgcn_ds_bpermute(idx, ws_[2 * ks + 1][hp & 1]);
                        wt[ks][hp] = ghigh ? v1 : v0;
                    }
            }

#pragma unroll
            for (int ks = 0; ks < 2; ++ks) {
                bf16x8 pa0 = *(const bf16x8*)&wt0[ks][0];
                bf16x8 pa1 = *(const bf16x8*)&wt1[ks][0];
#pragma unroll
                for (int dt = 0; dt < 4; ++dt) {
                    int d = dt * 16 + lr;
                    int xv = (ks * 4 + g) ^ (lr & 7) ^ (dt * 2 + (lr >> 3));
                    bf16x8 vf = *(const bf16x8*)&Vc[d * 64 + xv * 8];
                    if (act0) O[0][dt] = __builtin_amdgcn_mfma_f32_16x16x32_bf16(pa0, vf, O[0][dt], 0, 0, 0);
                    if (act1) O[1][dt] = __builtin_amdgcn_mfma_f32_16x16x32_bf16(pa1, vf, O[1][dt], 0, 0, 0);
                }
            }
            buf ^= 1;
        }

#pragma unroll
        for (int sub = 0; sub < 2; ++sub) {
            int lv = __builtin_bit_cast(int, l_[sub]);
#pragma unroll
            for (int r = 0; r < 4; ++r) {
                float lval = __builtin_bit_cast(float, __builtin_amdgcn_ds_bpermute(idxA[r], lv));
                float inv = __builtin_amdgcn_rcpf(lval);
                int q = q0w + sub * 16 + g * 4 + r;
#pragma unroll
                for (int dt = 0; dt < 4; ++dt)
                    y[(size_t)(b * 2048 + q) * 1024 + h * 64 + dt * 16 + lr] =
                        f2bf(O[sub][dt][r] * inv);
            }
        }
    };

    process(15 - p);
    __syncthreads();
    process(p);
}

// ---------------- residual + layernorm: out = base + LN(delta)*g+b ----------------
template <int WRITE_BF>
__global__ __launch_bounds__(256) void ln_kernel(const float* __restrict__ base,
                                                 const float* __restrict__ delta,
                                                 const float* __restrict__ gw,
                                                 const float* __restrict__ bw,
                                                 float* __restrict__ outf,
                                                 unsigned short* __restrict__ outb) {
    const int row = blockIdx.x;
    const int tid = threadIdx.x;
    const float* d = delta + (size_t)row * 1024;
    const float* bs = base + (size_t)row * 1024;
    float4 x = *(const float4*)&d[tid * 4];
    float s = x.x + x.y + x.z + x.w;
    float s2 = x.x * x.x + x.y * x.y + x.z * x.z + x.w * x.w;
#pragma unroll
    for (int off = 1; off < 64; off <<= 1) {
        s += __shfl_xor(s, off);
        s2 += __shfl_xor(s2, off);
    }
    __shared__ float red[8];
    if ((tid & 63) == 0) {
        red[tid >> 6] = s;
        red[4 + (tid >> 6)] = s2;
    }
    __syncthreads();
    s = red[0] + red[1] + red[2] + red[3];
    s2 = red[4] + red[5] + red[6] + red[7];
    float mu = s * (1.f / 1024.f);
    float var = s2 * (1.f / 1024.f) - mu * mu;
    float rsig = rsqrtf(var + 1e-5f);
    float4 bb = *(const float4*)&bs[tid * 4];
    float4 gv = *(const float4*)&gw[tid * 4];
    float4 bv = *(const float4*)&bw[tid * 4];
    float4 o;
    o.x = bb.x + (x.x - mu) * rsig * gv.x + bv.x;
    o.y = bb.y + (x.y - mu) * rsig * gv.y + bv.y;
    o.z = bb.z + (x.z - mu) * rsig * gv.z + bv.z;
    o.w = bb.w + (x.w - mu) * rsig * gv.w + bv.w;
    *(float4*)&outf[(size_t)row * 1024 + tid * 4] = o;
    if (WRITE_BF) {
        unsigned short* ob = outb + (size_t)row * 1024 + tid * 4;
        ob[0] = f2bf(o.x);
        ob[1] = f2bf(o.y);
        ob[2] = f2bf(o.z);
        ob[3] = f2bf(o.w);
    }
}

extern "C" void kernel_launch(void* const* d_in, const int* in_sizes, int n_in,
                              void* d_out, int out_size, void* d_ws, size_t ws_size,
                              hipStream_t stream) {
    const float* x = (const float*)d_in[0];
    const float* w_qkv = (const float*)d_in[1];
    const float* b_qkv = (const float*)d_in[2];
    const float* w_out = (const float*)d_in[3];
    const float* b_out = (const float*)d_in[4];
    const float* w1 = (const float*)d_in[5];
    const float* b1 = (const float*)d_in[6];
    const float* w2 = (const float*)d_in[7];
    const float* b2 = (const float*)d_in[8];
    const float* g1 = (const float*)d_in[9];
    const float* be1 = (const float*)d_in[10];
    const float* g2 = (const float*)d_in[11];
    const float* be2 = (const float*)d_in[12];

    const size_t MB = 1ull << 20;
    if (ws_size < 184 * MB) return;
    char* ws = (char*)d_ws;
    unsigned short* xb    = (unsigned short*)(ws + 0);         // 16MB (dead after qkv gemm)
    unsigned short* vtg   = (unsigned short*)(ws + 0);         // 16MB (V^T, lives during attn)
    unsigned short* wqkvt = (unsigned short*)(ws + 16 * MB);   // 6MB
    unsigned short* qkvb  = (unsigned short*)(ws + 22 * MB);   // 48MB
    unsigned short* hb    = (unsigned short*)(ws + 0);         // 64MB (reuse, MLP phase)
    unsigned short* woutt = (unsigned short*)(ws + 70 * MB);   // 2MB
    unsigned short* yb    = (unsigned short*)(ws + 72 * MB);   // 16MB
    float*          attnp = (float*)(ws + 88 * MB);            // 32MB
    float*          ff    = (float*)(ws + 88 * MB);            // 32MB (reuse)
    float*          x2f   = (float*)(ws + 120 * MB);           // 32MB
    unsigned short* x2b   = (unsigned short*)(ws + 152 * MB);  // 16MB
    unsigned short* w1t   = (unsigned short*)(ws + 168 * MB);  // 8MB
    unsigned short* w2t   = (unsigned short*)(ws + 176 * MB);  // 8MB

    // prep
    cvtbf_kernel<<<8192, 256, 0, stream>>>(x, xb);
    transpose_cvt_kernel<<<dim3(96, 32), dim3(32, 8), 0, stream>>>(w_qkv, wqkvt, 1024, 3072);
    transpose_cvt_kernel<<<dim3(32, 32), dim3(32, 8), 0, stream>>>(w_out, woutt, 1024, 1024);
    transpose_cvt_kernel<<<dim3(128, 32), dim3(32, 8), 0, stream>>>(w1, w1t, 1024, 4096);
    transpose_cvt_kernel<<<dim3(32, 128), dim3(32, 8), 0, stream>>>(w2, w2t, 4096, 1024);
    // qkv = x @ w_qkv + b_qkv  (bf16 out)  [M=8192 N=3072 K=1024]
    gemm256_kernel<256, 2, 4, 0, 1><<<384, 512, 0, stream>>>(xb, wqkvt, b_qkv, qkvb, 3072, 1024, 32);
    // V^T pre-transpose
    vtrans_kernel<<<dim3(32, 64), 256, 0, stream>>>(qkvb, vtg);
    // attention
    attn_kernel<<<dim3(8, 16, 4), 256, 0, stream>>>(qkvb, vtg, yb);
    // out proj (f32 out) [N=1024 K=1024]
    gemm256_kernel<128, 4, 2, 0, 0><<<256, 512, 0, stream>>>(yb, woutt, b_out, attnp, 1024, 1024, 32);
    // x2 = x + LN(attnp)
    ln_kernel<1><<<8192, 256, 0, stream>>>(x, attnp, g1, be1, x2f, x2b);
    // h = gelu(x2 @ w1 + b1) (bf16 out) [N=4096 K=1024]
    gemm256_kernel<256, 2, 4, 1, 1><<<512, 512, 0, stream>>>(x2b, w1t, b1, hb, 4096, 1024, 32);
    // f = h @ w2 + b2 (f32 out) [N=1024 K=4096]
    gemm256_kernel<128, 4, 2, 0, 0><<<256, 512, 0, stream>>>(hb, w2t, b2, ff, 1024, 4096, 32);
    // out = x2 + LN(f)
    ln_kernel<0><<<8192, 256, 0, stream>>>(x2f, ff, g2, be2, (float*)d_out, nullptr);
}

// Round 5
// 538.346 us; speedup vs baseline: 1.5273x; 1.2063x over previous
//
#include <hip/hip_runtime.h>
#include <hip/hip_bf16.h>

typedef unsigned short ushort_t;
using bf16x8 = __attribute__((ext_vector_type(8))) short;
using f32x4  = __attribute__((ext_vector_type(4))) float;

#define DEV __device__ __forceinline__

DEV unsigned short f2bf(float f) {
    unsigned int u = __builtin_bit_cast(unsigned int, f);
    u = (u + 0x7fffu + ((u >> 16) & 1u)) >> 16;
    return (unsigned short)u;
}

DEV int cvtpk_bf16(float lo, float hi) {
    int r;
    asm("v_cvt_pk_bf16_f32 %0, %1, %2" : "=v"(r) : "v"(lo), "v"(hi));
    return r;
}

DEV void gload16(const unsigned short* g, unsigned short* l) {
    __builtin_amdgcn_global_load_lds(
        (const __attribute__((address_space(1))) void*)g,
        (__attribute__((address_space(3))) void*)l, 16, 0, 0);
}

// tanh-form GELU
DEV float gelu_f(float v) {
    float u = v * (0.79788456f + 0.03567741f * v * v);
    float t = __builtin_amdgcn_exp2f(u * 2.88539008f);
    return v * t * __builtin_amdgcn_rcpf(t + 1.0f);
}

// ---------------- f32 -> bf16 convert ----------------
__global__ __launch_bounds__(256) void cvtbf_kernel(const float* __restrict__ in,
                                                    unsigned short* __restrict__ out) {
    int i = (blockIdx.x * 256 + threadIdx.x) * 4;
    float4 v = *(const float4*)&in[i];
    out[i + 0] = f2bf(v.x);
    out[i + 1] = f2bf(v.y);
    out[i + 2] = f2bf(v.z);
    out[i + 3] = f2bf(v.w);
}

// ---------------- transpose + convert: in[R,C] f32 -> out[C,R] bf16 ----------------
__global__ __launch_bounds__(256) void transpose_cvt_kernel(const float* __restrict__ in,
                                                            unsigned short* __restrict__ out,
                                                            int R, int C) {
    __shared__ float t[32][33];
    int tx = threadIdx.x, ty = threadIdx.y;
    int c0 = blockIdx.x * 32, r0 = blockIdx.y * 32;
#pragma unroll
    for (int i = 0; i < 4; ++i)
        t[ty + i * 8][tx] = in[(size_t)(r0 + ty + i * 8) * C + c0 + tx];
    __syncthreads();
#pragma unroll
    for (int i = 0; i < 4; ++i)
        out[(size_t)(c0 + ty + i * 8) * R + r0 + tx] = f2bf(t[tx][ty + i * 8]);
}

// ---------------- V transpose: qkvb V-part -> vtg[bh][64][2048] bf16 ----------------
__global__ __launch_bounds__(256) void vtrans_kernel(const unsigned short* __restrict__ qkvb,
                                                     unsigned short* __restrict__ vtg) {
    __shared__ unsigned short t[64 * 66];
    const int tid = threadIdx.x;
    const int t0 = blockIdx.x * 64;
    const int bh = blockIdx.y;
    const int b = bh >> 4, h = bh & 15;
    const unsigned short* src = qkvb + (size_t)(b * 2048 + t0) * 3072 + 2048 + h * 64;
#pragma unroll
    for (int c = 0; c < 2; ++c) {
        int cid = c * 256 + tid;
        int row = cid >> 3, cc = cid & 7;
        *(int4*)&t[row * 66 + cc * 8] = *(const int4*)&src[(size_t)row * 3072 + cc * 8];
    }
    __syncthreads();
    unsigned short* dst = vtg + (size_t)bh * 64 * 2048 + t0;
#pragma unroll
    for (int c = 0; c < 2; ++c) {
        int cid = c * 256 + tid;
        int d = cid >> 3, cc2 = cid & 7;
        bf16x8 v;
#pragma unroll
        for (int j = 0; j < 8; ++j) v[j] = (short)t[(cc2 * 8 + j) * 66 + d];
        *(bf16x8*)&dst[(size_t)d * 2048 + cc2 * 8] = v;
    }
}

// ---------------- GEMM BMx256, BK=64, 8 waves (2x4), K-half counted-vmcnt pipeline --
// Phase p = (ks=p>>1, mh=p&1). Stages for tile t+1 issued: p0:{A-Kh0(+B)}, p1:{B-Kh0},
// p2:{A-Kh1(+B)}, p3:{B-Kh1}. Waits: vmcnt(NW) at p0/p2 -> waited-for K-half group has
// >=3 phases of cover; NW loads always stay in flight across barriers (T3+T4).
template <int BM, int ACT, int OBF>
__global__ __launch_bounds__(512, 2) void gemm256_kernel(
    const unsigned short* __restrict__ A, const unsigned short* __restrict__ Bt,
    const float* __restrict__ bias, void* __restrict__ out,
    int N, int K, int gridNt) {
    constexpr int MF = BM / 32;          // M frags/wave (8 or 4)
    constexpr int MH = MF / 2;           // frags per mh phase (4 or 2)
    constexpr int ACH = BM * 8;          // A chunks per K-tile
    constexpr int ALD = BM / 64;         // A loads/thread/K-tile (4 or 2)
    constexpr int LB = (BM == 256) ? 8 : 7;
    __shared__ __align__(16) unsigned short lA[2][ACH * 8];
    __shared__ __align__(16) unsigned short lB[2][2048 * 8];
    const int tid = threadIdx.x;
    const int lane = tid & 63, wid = tid >> 6;
    const int g = lane >> 4, lr = lane & 15;
    const int wm = wid >> 2, wn = wid & 3;

    // XCD-aware bijective swizzle; row-major work id within XCD chunk (A-panel L2 reuse)
    const int nwg = gridDim.x, cpx = nwg >> 3, bid = blockIdx.x;
    const int wkid = (bid & 7) * cpx + (bid >> 3);
    const int mt = wkid / gridNt, nt = wkid % gridNt;
    const int m0 = mt * BM, n0 = nt * 256;

    auto stageA = [&](int s, int kt, int bb) {  // s in [0, ALD)
        int c = s * 512 + tid;
        int row = c & (BM - 1), kb = c >> LB;
        gload16(&A[(size_t)(m0 + row) * K + kt * 64 + kb * 8],
                &lA[bb][(size_t)(s * 512 + (tid & ~63)) * 8]);
    };
    auto stageB = [&](int s, int kt, int bb) {  // s in [0, 4)
        int c = s * 512 + tid;
        int row = c & 255, kb = c >> 8;
        gload16(&Bt[(size_t)(n0 + row) * K + kt * 64 + kb * 8],
                &lB[bb][(size_t)(s * 512 + (tid & ~63)) * 8]);
    };

    f32x4 acc[MF][4] = {};
    bf16x8 af[MH];
    bf16x8 bfr[4];

    const int nkt = K >> 6;
    // prologue: stage tile 0 into buf 0, K-half groups in order
    if constexpr (BM == 256) {
        stageA(0, 0, 0); stageA(1, 0, 0); stageB(0, 0, 0); stageB(1, 0, 0);
        stageA(2, 0, 0); stageA(3, 0, 0); stageB(2, 0, 0); stageB(3, 0, 0);
    } else {
        stageA(0, 0, 0); stageB(0, 0, 0); stageB(1, 0, 0);
        stageA(1, 0, 0); stageB(2, 0, 0); stageB(3, 0, 0);
    }

    for (int kt = 0; kt < nkt; ++kt) {
        const int b = kt & 1;
        const int ktn = kt + 1;
        const bool more = (ktn < nkt);
#pragma unroll
        for (int p = 0; p < 4; ++p) {
            const int ks = p >> 1, mh = p & 1;
            if (p == 0) {
                if constexpr (BM == 256) asm volatile("s_waitcnt vmcnt(4)" ::: "memory");
                else                     asm volatile("s_waitcnt vmcnt(3)" ::: "memory");
                __builtin_amdgcn_s_barrier();
                __builtin_amdgcn_sched_barrier(0);
            } else if (p == 2) {
                if (more) {
                    if constexpr (BM == 256) asm volatile("s_waitcnt vmcnt(4)" ::: "memory");
                    else                     asm volatile("s_waitcnt vmcnt(3)" ::: "memory");
                } else {
                    asm volatile("s_waitcnt vmcnt(0)" ::: "memory");
                }
                __builtin_amdgcn_s_barrier();
                __builtin_amdgcn_sched_barrier(0);
            }
            // ds_read fragments from buf b
#pragma unroll
            for (int mf2 = 0; mf2 < MH; ++mf2) {
                int row = wm * (BM / 2) + (mh * MH + mf2) * 16 + lr;
                int c = (ks * 4 + g) * BM + row;
                af[mf2] = *(const bf16x8*)&lA[b][(size_t)c * 8];
            }
            if (mh == 0) {  // B frags cached across the two mh phases of this ks
#pragma unroll
                for (int nf = 0; nf < 4; ++nf) {
                    int row = wn * 64 + nf * 16 + lr;
                    int c = (ks * 4 + g) * 256 + row;
                    bfr[nf] = *(const bf16x8*)&lB[b][(size_t)c * 8];
                }
            }
            // stage next tile (K-half groups)
            if (more) {
                if constexpr (BM == 256) {
                    if (p == 0) { stageA(0, ktn, b ^ 1); stageA(1, ktn, b ^ 1); }
                    else if (p == 1) { stageB(0, ktn, b ^ 1); stageB(1, ktn, b ^ 1); }
                    else if (p == 2) { stageA(2, ktn, b ^ 1); stageA(3, ktn, b ^ 1); }
                    else { stageB(2, ktn, b ^ 1); stageB(3, ktn, b ^ 1); }
                } else {
                    if (p == 0) { stageA(0, ktn, b ^ 1); stageB(0, ktn, b ^ 1); }
                    else if (p == 1) { stageB(1, ktn, b ^ 1); }
                    else if (p == 2) { stageA(1, ktn, b ^ 1); stageB(2, ktn, b ^ 1); }
                    else { stageB(3, ktn, b ^ 1); }
                }
            }
            __builtin_amdgcn_sched_barrier(0);
            __builtin_amdgcn_s_barrier();
            asm volatile("s_waitcnt lgkmcnt(0)" ::: "memory");
            __builtin_amdgcn_sched_barrier(0);
            __builtin_amdgcn_s_setprio(1);
#pragma unroll
            for (int mf2 = 0; mf2 < MH; ++mf2)
#pragma unroll
                for (int nf = 0; nf < 4; ++nf) {
                    int mf = mh * MH + mf2;
                    acc[mf][nf] = __builtin_amdgcn_mfma_f32_16x16x32_bf16(
                        af[mf2], bfr[nf], acc[mf][nf], 0, 0, 0);
                }
            __builtin_amdgcn_s_setprio(0);
            __builtin_amdgcn_sched_barrier(0);
        }
    }

    // epilogue: bias (+GELU) and store
#pragma unroll
    for (int mf = 0; mf < MF; ++mf) {
#pragma unroll
        for (int nf = 0; nf < 4; ++nf) {
            int col = n0 + wn * 64 + nf * 16 + lr;
            float bv = bias[col];
#pragma unroll
            for (int r = 0; r < 4; ++r) {
                int row = m0 + wm * (BM / 2) + mf * 16 + g * 4 + r;
                float v = acc[mf][nf][r] + bv;
                if (ACT == 1) v = gelu_f(v);
                if (OBF)
                    ((unsigned short*)out)[(size_t)row * N + col] = f2bf(v);
                else
                    ((float*)out)[(size_t)row * N + col] = v;
            }
        }
    }
}

// ---------------- flash attention v3 ----------------
__global__ __launch_bounds__(256) void attn_kernel(const unsigned short* __restrict__ qkv,
                                                   const unsigned short* __restrict__ vtg,
                                                   unsigned short* __restrict__ y) {
    __shared__ unsigned short Kl[2][4096];
    __shared__ unsigned short Vl[2][4096];
    const int tid = threadIdx.x, lane = tid & 63, w = tid >> 6;
    const int g = lane >> 4, lr = lane & 15;
    const int p = blockIdx.x, h = blockIdx.y, b = blockIdx.z;
    const int bh = b * 16 + h;
    const size_t rs3 = 3072;
    const unsigned short* qbase = qkv + (size_t)b * 2048 * rs3 + h * 64;
    const unsigned short* kbase = qbase + 1024;
    const unsigned short* vbase = vtg + (size_t)bh * 64 * 2048;

    int ksoff[2], vsoff[2], ldoff[2];
#pragma unroll
    for (int c = 0; c < 2; ++c) {
        int row = w * 16 + c * 8 + (lane >> 3);
        int ccs = (lane & 7) ^ (row & 7) ^ (row >> 3);
        ksoff[c] = row * 3072 + ccs * 8;
        vsoff[c] = row * 2048 + ccs * 8;
        ldoff[c] = (w * 16 + c * 8) * 64;
    }

    const int idxP0 = 4 * (32 * (g & 1) + lr);
    const int idxP1 = idxP0 + 64;
    int idxA[4];
#pragma unroll
    for (int r = 0; r < 4; ++r) idxA[r] = 4 * (g * 20 + r);
    const bool ghigh = (g >> 1) != 0;
    const float qscale = 0.125f * 1.44269504089f;

    auto process = [&](int J) {
        const int q0w = J * 128 + w * 32;
        const int ktend = 2 * J + 2;
#pragma unroll
        for (int c = 0; c < 2; ++c) {
            gload16(&kbase[ksoff[c]], &Kl[0][ldoff[c]]);
            gload16(&vbase[vsoff[c]], &Vl[0][ldoff[c]]);
        }
        int qf[2][2][4];
#pragma unroll
        for (int sub = 0; sub < 2; ++sub)
#pragma unroll
            for (int f = 0; f < 2; ++f) {
                int4 v = *(const int4*)&qbase[(size_t)(q0w + sub * 16 + lr) * rs3 + f * 32 + g * 8];
                int vv[4] = {v.x, v.y, v.z, v.w};
#pragma unroll
                for (int i = 0; i < 4; ++i) {
                    unsigned int u = (unsigned int)vv[i];
                    float lo = __builtin_bit_cast(float, u << 16) * qscale;
                    float hi = __builtin_bit_cast(float, u & 0xffff0000u) * qscale;
                    qf[sub][f][i] = cvtpk_bf16(lo, hi);
                }
            }

        f32x4 O[2][4] = {};
        float m_[2] = {-3.0e38f, -3.0e38f}, l_[2] = {0.f, 0.f};

        int buf = 0;
        for (int kt = 0; kt < ktend; ++kt) {
            asm volatile("s_waitcnt vmcnt(0)" ::: "memory");
            __builtin_amdgcn_s_barrier();
            __builtin_amdgcn_sched_barrier(0);
            if (kt + 1 < ktend) {
#pragma unroll
                for (int c = 0; c < 2; ++c) {
                    gload16(&kbase[(size_t)(kt + 1) * 64 * 3072 + ksoff[c]], &Kl[buf ^ 1][ldoff[c]]);
                    gload16(&vbase[vsoff[c] + (kt + 1) * 64], &Vl[buf ^ 1][ldoff[c]]);
                }
            }
            const unsigned short* Kc = Kl[buf];
            const unsigned short* Vc = Vl[buf];

            const bool act0 = (kt * 64) <= (q0w + 15);
            const bool act1 = (kt * 64) <= (q0w + 31);

            f32x4 s0[4], s1[4];
#pragma unroll
            for (int st = 0; st < 4; ++st) {
                int rbase = (st * 16 + lr) * 64;
                int sw = (lr & 7) ^ (st * 2 + (lr >> 3));
                bf16x8 kf0 = *(const bf16x8*)&Kc[rbase + ((g ^ sw) * 8)];
                bf16x8 kf1 = *(const bf16x8*)&Kc[rbase + (((4 + g) ^ sw) * 8)];
                if (act0) {
                    f32x4 a = {};
                    a = __builtin_amdgcn_mfma_f32_16x16x32_bf16(kf0, *(const bf16x8*)&qf[0][0], a, 0, 0, 0);
                    a = __builtin_amdgcn_mfma_f32_16x16x32_bf16(kf1, *(const bf16x8*)&qf[0][1], a, 0, 0, 0);
                    s0[st] = a;
                }
                if (act1) {
                    f32x4 a = {};
                    a = __builtin_amdgcn_mfma_f32_16x16x32_bf16(kf0, *(const bf16x8*)&qf[1][0], a, 0, 0, 0);
                    a = __builtin_amdgcn_mfma_f32_16x16x32_bf16(kf1, *(const bf16x8*)&qf[1][1], a, 0, 0, 0);
                    s1[st] = a;
                }
            }

            int wt0[2][4], wt1[2][4];
#pragma unroll
            for (int sub = 0; sub < 2; ++sub) {
                if (sub == 0 && !act0) continue;
                if (sub == 1 && !act1) continue;
                f32x4* s = (sub == 0) ? s0 : s1;
                const int qmin = q0w + sub * 16;
                if (kt * 64 + 63 > qmin) {
                    int qv = qmin + lr;
#pragma unroll
                    for (int st = 0; st < 4; ++st) {
                        int keyb = kt * 64 + st * 16 + g * 4;
#pragma unroll
                        for (int r = 0; r < 4; ++r)
                            if (keyb + r > qv) s[st][r] = -3.0e38f;
                    }
                }
                float mx = fmaxf(fmaxf(s[0][0], s[0][1]), fmaxf(s[0][2], s[0][3]));
#pragma unroll
                for (int st = 1; st < 4; ++st)
                    mx = fmaxf(mx, fmaxf(fmaxf(s[st][0], s[st][1]), fmaxf(s[st][2], s[st][3])));
                mx = fmaxf(mx, __shfl_xor(mx, 16));
                mx = fmaxf(mx, __shfl_xor(mx, 32));
                float mold = m_[sub];
                float mnew = fmaxf(mold, mx);
                float alpha = __builtin_amdgcn_exp2f(mold - mnew);
                m_[sub] = mnew;
                float rs = 0.f;
#pragma unroll
                for (int st = 0; st < 4; ++st)
#pragma unroll
                    for (int r = 0; r < 4; ++r) {
                        float pp = __builtin_amdgcn_exp2f(s[st][r] - mnew);
                        s[st][r] = pp;
                        rs += pp;
                    }
                rs += __shfl_xor(rs, 16);
                rs += __shfl_xor(rs, 32);
                l_[sub] = l_[sub] * alpha + rs;
                int av = __builtin_bit_cast(int, alpha);
                f32x4* Os = O[sub];
#pragma unroll
                for (int r = 0; r < 4; ++r) {
                    float ar = __builtin_bit_cast(float, __builtin_amdgcn_ds_bpermute(idxA[r], av));
#pragma unroll
                    for (int dt = 0; dt < 4; ++dt) Os[dt][r] *= ar;
                }
                int ws_[4][2];
#pragma unroll
                for (int st = 0; st < 4; ++st) {
                    ws_[st][0] = cvtpk_bf16(s[st][0], s[st][1]);
                    ws_[st][1] = cvtpk_bf16(s[st][2], s[st][3]);
                }
                int(*wt)[4] = (sub == 0) ? wt0 : wt1;
#pragma unroll
                for (int ks = 0; ks < 2; ++ks)
#pragma unroll
                    for (int hp = 0; hp < 4; ++hp) {
                        int idx = (hp < 2) ? idxP0 : idxP1;
                        int v0 = __builtin_amdgcn_ds_bpermute(idx, ws_[2 * ks][hp & 1]);
                        int v1 = __builtin_amdgcn_ds_bpermute(idx, ws_[2 * ks + 1][hp & 1]);
                        wt[ks][hp] = ghigh ? v1 : v0;
                    }
            }

#pragma unroll
            for (int ks = 0; ks < 2; ++ks) {
                bf16x8 pa0 = *(const bf16x8*)&wt0[ks][0];
                bf16x8 pa1 = *(const bf16x8*)&wt1[ks][0];
#pragma unroll
                for (int dt = 0; dt < 4; ++dt) {
                    int d = dt * 16 + lr;
                    int xv = (ks * 4 + g) ^ (lr & 7) ^ (dt * 2 + (lr >> 3));
                    bf16x8 vf = *(const bf16x8*)&Vc[d * 64 + xv * 8];
                    if (act0) O[0][dt] = __builtin_amdgcn_mfma_f32_16x16x32_bf16(pa0, vf, O[0][dt], 0, 0, 0);
                    if (act1) O[1][dt] = __builtin_amdgcn_mfma_f32_16x16x32_bf16(pa1, vf, O[1][dt], 0, 0, 0);
                }
            }
            buf ^= 1;
        }

#pragma unroll
        for (int sub = 0; sub < 2; ++sub) {
            int lv = __builtin_bit_cast(int, l_[sub]);
#pragma unroll
            for (int r = 0; r < 4; ++r) {
                float lval = __builtin_bit_cast(float, __builtin_amdgcn_ds_bpermute(idxA[r], lv));
                float inv = __builtin_amdgcn_rcpf(lval);
                int q = q0w + sub * 16 + g * 4 + r;
#pragma unroll
                for (int dt = 0; dt < 4; ++dt)
                    y[(size_t)(b * 2048 + q) * 1024 + h * 64 + dt * 16 + lr] =
                        f2bf(O[sub][dt][r] * inv);
            }
        }
    };

    process(15 - p);
    __syncthreads();
    process(p);
}

// ---------------- residual + layernorm: out = base + LN(delta)*g+b ----------------
template <int WRITE_BF>
__global__ __launch_bounds__(256) void ln_kernel(const float* __restrict__ base,
                                                 const float* __restrict__ delta,
                                                 const float* __restrict__ gw,
                                                 const float* __restrict__ bw,
                                                 float* __restrict__ outf,
                                                 unsigned short* __restrict__ outb) {
    const int row = blockIdx.x;
    const int tid = threadIdx.x;
    const float* d = delta + (size_t)row * 1024;
    const float* bs = base + (size_t)row * 1024;
    float4 x = *(const float4*)&d[tid * 4];
    float s = x.x + x.y + x.z + x.w;
    float s2 = x.x * x.x + x.y * x.y + x.z * x.z + x.w * x.w;
#pragma unroll
    for (int off = 1; off < 64; off <<= 1) {
        s += __shfl_xor(s, off);
        s2 += __shfl_xor(s2, off);
    }
    __shared__ float red[8];
    if ((tid & 63) == 0) {
        red[tid >> 6] = s;
        red[4 + (tid >> 6)] = s2;
    }
    __syncthreads();
    s = red[0] + red[1] + red[2] + red[3];
    s2 = red[4] + red[5] + red[6] + red[7];
    float mu = s * (1.f / 1024.f);
    float var = s2 * (1.f / 1024.f) - mu * mu;
    float rsig = rsqrtf(var + 1e-5f);
    float4 bb = *(const float4*)&bs[tid * 4];
    float4 gv = *(const float4*)&gw[tid * 4];
    float4 bv = *(const float4*)&bw[tid * 4];
    float4 o;
    o.x = bb.x + (x.x - mu) * rsig * gv.x + bv.x;
    o.y = bb.y + (x.y - mu) * rsig * gv.y + bv.y;
    o.z = bb.z + (x.z - mu) * rsig * gv.z + bv.z;
    o.w = bb.w + (x.w - mu) * rsig * gv.w + bv.w;
    *(float4*)&outf[(size_t)row * 1024 + tid * 4] = o;
    if (WRITE_BF) {
        unsigned short* ob = outb + (size_t)row * 1024 + tid * 4;
        ob[0] = f2bf(o.x);
        ob[1] = f2bf(o.y);
        ob[2] = f2bf(o.z);
        ob[3] = f2bf(o.w);
    }
}

extern "C" void kernel_launch(void* const* d_in, const int* in_sizes, int n_in,
                              void* d_out, int out_size, void* d_ws, size_t ws_size,
                              hipStream_t stream) {
    const float* x = (const float*)d_in[0];
    const float* w_qkv = (const float*)d_in[1];
    const float* b_qkv = (const float*)d_in[2];
    const float* w_out = (const float*)d_in[3];
    const float* b_out = (const float*)d_in[4];
    const float* w1 = (const float*)d_in[5];
    const float* b1 = (const float*)d_in[6];
    const float* w2 = (const float*)d_in[7];
    const float* b2 = (const float*)d_in[8];
    const float* g1 = (const float*)d_in[9];
    const float* be1 = (const float*)d_in[10];
    const float* g2 = (const float*)d_in[11];
    const float* be2 = (const float*)d_in[12];

    const size_t MB = 1ull << 20;
    if (ws_size < 184 * MB) return;
    char* ws = (char*)d_ws;
    unsigned short* xb    = (unsigned short*)(ws + 0);         // 16MB (dead after qkv gemm)
    unsigned short* vtg   = (unsigned short*)(ws + 0);         // 16MB (V^T, lives during attn)
    unsigned short* wqkvt = (unsigned short*)(ws + 16 * MB);   // 6MB
    unsigned short* qkvb  = (unsigned short*)(ws + 22 * MB);   // 48MB
    unsigned short* hb    = (unsigned short*)(ws + 0);         // 64MB (reuse, MLP phase)
    unsigned short* woutt = (unsigned short*)(ws + 70 * MB);   // 2MB
    unsigned short* yb    = (unsigned short*)(ws + 72 * MB);   // 16MB
    float*          attnp = (float*)(ws + 88 * MB);            // 32MB
    float*          ff    = (float*)(ws + 88 * MB);            // 32MB (reuse)
    float*          x2f   = (float*)(ws + 120 * MB);           // 32MB
    unsigned short* x2b   = (unsigned short*)(ws + 152 * MB);  // 16MB
    unsigned short* w1t   = (unsigned short*)(ws + 168 * MB);  // 8MB
    unsigned short* w2t   = (unsigned short*)(ws + 176 * MB);  // 8MB

    // prep
    cvtbf_kernel<<<8192, 256, 0, stream>>>(x, xb);
    transpose_cvt_kernel<<<dim3(96, 32), dim3(32, 8), 0, stream>>>(w_qkv, wqkvt, 1024, 3072);
    transpose_cvt_kernel<<<dim3(32, 32), dim3(32, 8), 0, stream>>>(w_out, woutt, 1024, 1024);
    transpose_cvt_kernel<<<dim3(128, 32), dim3(32, 8), 0, stream>>>(w1, w1t, 1024, 4096);
    transpose_cvt_kernel<<<dim3(32, 128), dim3(32, 8), 0, stream>>>(w2, w2t, 4096, 1024);
    // qkv = x @ w_qkv + b_qkv (bf16 out) [M=8192 N=3072 K=1024]: 32mt x 12nt
    gemm256_kernel<256, 0, 1><<<384, 512, 0, stream>>>(xb, wqkvt, b_qkv, qkvb, 3072, 1024, 12);
    // V^T pre-transpose
    vtrans_kernel<<<dim3(32, 64), 256, 0, stream>>>(qkvb, vtg);
    // attention
    attn_kernel<<<dim3(8, 16, 4), 256, 0, stream>>>(qkvb, vtg, yb);
    // out proj (f32 out) [N=1024 K=1024]: BM=128 -> 64mt x 4nt
    gemm256_kernel<128, 0, 0><<<256, 512, 0, stream>>>(yb, woutt, b_out, attnp, 1024, 1024, 4);
    // x2 = x + LN(attnp)
    ln_kernel<1><<<8192, 256, 0, stream>>>(x, attnp, g1, be1, x2f, x2b);
    // h = gelu(x2 @ w1 + b1) (bf16 out) [N=4096 K=1024]: 32mt x 16nt
    gemm256_kernel<256, 1, 1><<<512, 512, 0, stream>>>(x2b, w1t, b1, hb, 4096, 1024, 16);
    // f = h @ w2 + b2 (f32 out) [N=1024 K=4096]: BM=128 -> 64mt x 4nt
    gemm256_kernel<128, 0, 0><<<256, 512, 0, stream>>>(hb, w2t, b2, ff, 1024, 4096, 4);
    // out = x2 + LN(f)
    ln_kernel<0><<<8192, 256, 0, stream>>>(x2f, ff, g2, be2, (float*)d_out, nullptr);
}

// Round 6
// 511.614 us; speedup vs baseline: 1.6071x; 1.0522x over previous
//
#include <hip/hip_runtime.h>
#include <hip/hip_bf16.h>

typedef unsigned short ushort_t;
using bf16x8 = __attribute__((ext_vector_type(8))) short;
using f32x4  = __attribute__((ext_vector_type(4))) float;

#define DEV __device__ __forceinline__

DEV unsigned short f2bf(float f) {
    unsigned int u = __builtin_bit_cast(unsigned int, f);
    u = (u + 0x7fffu + ((u >> 16) & 1u)) >> 16;
    return (unsigned short)u;
}

DEV int cvtpk_bf16(float lo, float hi) {
    int r;
    asm("v_cvt_pk_bf16_f32 %0, %1, %2" : "=v"(r) : "v"(lo), "v"(hi));
    return r;
}

DEV void gload16(const unsigned short* g, unsigned short* l) {
    __builtin_amdgcn_global_load_lds(
        (const __attribute__((address_space(1))) void*)g,
        (__attribute__((address_space(3))) void*)l, 16, 0, 0);
}

// tanh-form GELU
DEV float gelu_f(float v) {
    float u = v * (0.79788456f + 0.03567741f * v * v);
    float t = __builtin_amdgcn_exp2f(u * 2.88539008f);
    return v * t * __builtin_amdgcn_rcpf(t + 1.0f);
}

// ---------------- f32 -> bf16 convert ----------------
__global__ __launch_bounds__(256) void cvtbf_kernel(const float* __restrict__ in,
                                                    unsigned short* __restrict__ out) {
    int i = (blockIdx.x * 256 + threadIdx.x) * 4;
    float4 v = *(const float4*)&in[i];
    out[i + 0] = f2bf(v.x);
    out[i + 1] = f2bf(v.y);
    out[i + 2] = f2bf(v.z);
    out[i + 3] = f2bf(v.w);
}

// ---------------- transpose + convert: in[R,C] f32 -> out[C,R] bf16 ----------------
__global__ __launch_bounds__(256) void transpose_cvt_kernel(const float* __restrict__ in,
                                                            unsigned short* __restrict__ out,
                                                            int R, int C) {
    __shared__ float t[32][33];
    int tx = threadIdx.x, ty = threadIdx.y;
    int c0 = blockIdx.x * 32, r0 = blockIdx.y * 32;
#pragma unroll
    for (int i = 0; i < 4; ++i)
        t[ty + i * 8][tx] = in[(size_t)(r0 + ty + i * 8) * C + c0 + tx];
    __syncthreads();
#pragma unroll
    for (int i = 0; i < 4; ++i)
        out[(size_t)(c0 + ty + i * 8) * R + r0 + tx] = f2bf(t[tx][ty + i * 8]);
}

// ---------------- V transpose: qkvb V-part -> vtg[bh][64][2048] bf16 ----------------
__global__ __launch_bounds__(256) void vtrans_kernel(const unsigned short* __restrict__ qkvb,
                                                     unsigned short* __restrict__ vtg) {
    __shared__ unsigned short t[64 * 66];
    const int tid = threadIdx.x;
    const int t0 = blockIdx.x * 64;
    const int bh = blockIdx.y;
    const int b = bh >> 4, h = bh & 15;
    const unsigned short* src = qkvb + (size_t)(b * 2048 + t0) * 3072 + 2048 + h * 64;
#pragma unroll
    for (int c = 0; c < 2; ++c) {
        int cid = c * 256 + tid;
        int row = cid >> 3, cc = cid & 7;
        *(int4*)&t[row * 66 + cc * 8] = *(const int4*)&src[(size_t)row * 3072 + cc * 8];
    }
    __syncthreads();
    unsigned short* dst = vtg + (size_t)bh * 64 * 2048 + t0;
#pragma unroll
    for (int c = 0; c < 2; ++c) {
        int cid = c * 256 + tid;
        int d = cid >> 3, cc2 = cid & 7;
        bf16x8 v;
#pragma unroll
        for (int j = 0; j < 8; ++j) v[j] = (short)t[(cc2 * 8 + j) * 66 + d];
        *(bf16x8*)&dst[(size_t)d * 2048 + cc2 * 8] = v;
    }
}

// ---------------- GEMM BMx256, BK=64, 8 waves (2x4), 2 phases/K-tile ----------------
// Phase ks: {vmcnt(NW); s_barrier; memfence; ds_read 12 b128; stage K-half group of
// kt+1; setprio(1); MF*4 MFMA; setprio(0)}. Counted vmcnt: group Kh_ks(kt) was issued
// 2 phases earlier; NW loads stay in flight across every barrier. No sched_barrier,
// no inline lgkmcnt -- compiler schedules ds_read->MFMA with fine-grained waits.
template <int BM, int ACT, int OBF>
__global__ __launch_bounds__(512, 2) void gemm256_kernel(
    const unsigned short* __restrict__ A, const unsigned short* __restrict__ Bt,
    const float* __restrict__ bias, void* __restrict__ out,
    int N, int K, int gridNt) {
    constexpr int MF = BM / 32;          // M frags/wave (8 or 4)
    constexpr int ALD = BM / 64;         // A loads/thread/K-tile (4 or 2)
    constexpr int NW = ALD / 2 + 2;      // loads per K-half group (4 or 3)
    constexpr int LB = (BM == 256) ? 8 : 7;
    __shared__ __align__(16) unsigned short lA[2][BM * 64];
    __shared__ __align__(16) unsigned short lB[2][256 * 64];
    const int tid = threadIdx.x;
    const int lane = tid & 63, wid = tid >> 6;
    const int g = lane >> 4, lr = lane & 15;
    const int wm = wid >> 2, wn = wid & 3;

    // XCD-aware bijective swizzle; row-major work id within XCD chunk (A-panel L2 reuse)
    const int nwg = gridDim.x, cpx = nwg >> 3, bid = blockIdx.x;
    const int wkid = (bid & 7) * cpx + (bid >> 3);
    const int mt = wkid / gridNt, nt = wkid % gridNt;
    const int m0 = mt * BM, n0 = nt * 256;

    auto stageA = [&](int s, int kt, int bb) {  // s in [0, ALD)
        int c = s * 512 + tid;
        int row = c & (BM - 1), kb = c >> LB;
        gload16(&A[(size_t)(m0 + row) * K + kt * 64 + kb * 8],
                &lA[bb][(size_t)(s * 512 + (tid & ~63)) * 8]);
    };
    auto stageB = [&](int s, int kt, int bb) {  // s in [0, 4)
        int c = s * 512 + tid;
        int row = c & 255, kb = c >> 8;
        gload16(&Bt[(size_t)(n0 + row) * K + kt * 64 + kb * 8],
                &lB[bb][(size_t)(s * 512 + (tid & ~63)) * 8]);
    };
    auto stageKh = [&](int half, int kt, int bb) {
        if constexpr (BM == 256) {
            stageA(half * 2 + 0, kt, bb);
            stageA(half * 2 + 1, kt, bb);
            stageB(half * 2 + 0, kt, bb);
            stageB(half * 2 + 1, kt, bb);
        } else {
            stageA(half, kt, bb);
            stageB(half * 2 + 0, kt, bb);
            stageB(half * 2 + 1, kt, bb);
        }
    };

    f32x4 acc[MF][4] = {};
    bf16x8 af[MF];
    bf16x8 bfr[4];

    const int nkt = K >> 6;
    // prologue: stage tile 0 into buf 0, K-half groups in issue order
    stageKh(0, 0, 0);
    stageKh(1, 0, 0);

    for (int kt = 0; kt < nkt; ++kt) {
        const int b = kt & 1;
        const bool more = (kt + 1 < nkt);
#pragma unroll
        for (int ks = 0; ks < 2; ++ks) {
            if (ks == 1 && !more)
                asm volatile("s_waitcnt vmcnt(0)" ::: "memory");
            else if constexpr (BM == 256)
                asm volatile("s_waitcnt vmcnt(4)" ::: "memory");
            else
                asm volatile("s_waitcnt vmcnt(3)" ::: "memory");
            __builtin_amdgcn_s_barrier();
            asm volatile("" ::: "memory");  // keep LDS reads below the barrier
            // ds_read all fragments for this ks
#pragma unroll
            for (int mf = 0; mf < MF; ++mf) {
                int c = (ks * 4 + g) * BM + wm * (BM / 2) + mf * 16 + lr;
                af[mf] = *(const bf16x8*)&lA[b][(size_t)c * 8];
            }
#pragma unroll
            for (int nf = 0; nf < 4; ++nf) {
                int c = (ks * 4 + g) * 256 + wn * 64 + nf * 16 + lr;
                bfr[nf] = *(const bf16x8*)&lB[b][(size_t)c * 8];
            }
            // stage next K-tile's matching K-half group
            if (more) stageKh(ks, kt + 1, b ^ 1);
            __builtin_amdgcn_s_setprio(1);
#pragma unroll
            for (int mf = 0; mf < MF; ++mf)
#pragma unroll
                for (int nf = 0; nf < 4; ++nf)
                    acc[mf][nf] = __builtin_amdgcn_mfma_f32_16x16x32_bf16(
                        af[mf], bfr[nf], acc[mf][nf], 0, 0, 0);
            __builtin_amdgcn_s_setprio(0);
        }
    }

    // epilogue: bias (+GELU) and store
#pragma unroll
    for (int mf = 0; mf < MF; ++mf) {
#pragma unroll
        for (int nf = 0; nf < 4; ++nf) {
            int col = n0 + wn * 64 + nf * 16 + lr;
            float bv = bias[col];
#pragma unroll
            for (int r = 0; r < 4; ++r) {
                int row = m0 + wm * (BM / 2) + mf * 16 + g * 4 + r;
                float v = acc[mf][nf][r] + bv;
                if (ACT == 1) v = gelu_f(v);
                if (OBF)
                    ((unsigned short*)out)[(size_t)row * N + col] = f2bf(v);
                else
                    ((float*)out)[(size_t)row * N + col] = v;
            }
        }
    }
}

// ---------------- flash attention v3 ----------------
__global__ __launch_bounds__(256) void attn_kernel(const unsigned short* __restrict__ qkv,
                                                   const unsigned short* __restrict__ vtg,
                                                   unsigned short* __restrict__ y) {
    __shared__ unsigned short Kl[2][4096];
    __shared__ unsigned short Vl[2][4096];
    const int tid = threadIdx.x, lane = tid & 63, w = tid >> 6;
    const int g = lane >> 4, lr = lane & 15;
    const int p = blockIdx.x, h = blockIdx.y, b = blockIdx.z;
    const int bh = b * 16 + h;
    const size_t rs3 = 3072;
    const unsigned short* qbase = qkv + (size_t)b * 2048 * rs3 + h * 64;
    const unsigned short* kbase = qbase + 1024;
    const unsigned short* vbase = vtg + (size_t)bh * 64 * 2048;

    int ksoff[2], vsoff[2], ldoff[2];
#pragma unroll
    for (int c = 0; c < 2; ++c) {
        int row = w * 16 + c * 8 + (lane >> 3);
        int ccs = (lane & 7) ^ (row & 7) ^ (row >> 3);
        ksoff[c] = row * 3072 + ccs * 8;
        vsoff[c] = row * 2048 + ccs * 8;
        ldoff[c] = (w * 16 + c * 8) * 64;
    }

    const int idxP0 = 4 * (32 * (g & 1) + lr);
    const int idxP1 = idxP0 + 64;
    int idxA[4];
#pragma unroll
    for (int r = 0; r < 4; ++r) idxA[r] = 4 * (g * 20 + r);
    const bool ghigh = (g >> 1) != 0;
    const float qscale = 0.125f * 1.44269504089f;

    auto process = [&](int J) {
        const int q0w = J * 128 + w * 32;
        const int ktend = 2 * J + 2;
#pragma unroll
        for (int c = 0; c < 2; ++c) {
            gload16(&kbase[ksoff[c]], &Kl[0][ldoff[c]]);
            gload16(&vbase[vsoff[c]], &Vl[0][ldoff[c]]);
        }
        int qf[2][2][4];
#pragma unroll
        for (int sub = 0; sub < 2; ++sub)
#pragma unroll
            for (int f = 0; f < 2; ++f) {
                int4 v = *(const int4*)&qbase[(size_t)(q0w + sub * 16 + lr) * rs3 + f * 32 + g * 8];
                int vv[4] = {v.x, v.y, v.z, v.w};
#pragma unroll
                for (int i = 0; i < 4; ++i) {
                    unsigned int u = (unsigned int)vv[i];
                    float lo = __builtin_bit_cast(float, u << 16) * qscale;
                    float hi = __builtin_bit_cast(float, u & 0xffff0000u) * qscale;
                    qf[sub][f][i] = cvtpk_bf16(lo, hi);
                }
            }

        f32x4 O[2][4] = {};
        float m_[2] = {-3.0e38f, -3.0e38f}, l_[2] = {0.f, 0.f};

        int buf = 0;
        for (int kt = 0; kt < ktend; ++kt) {
            asm volatile("s_waitcnt vmcnt(0)" ::: "memory");
            __builtin_amdgcn_s_barrier();
            asm volatile("" ::: "memory");
            if (kt + 1 < ktend) {
#pragma unroll
                for (int c = 0; c < 2; ++c) {
                    gload16(&kbase[(size_t)(kt + 1) * 64 * 3072 + ksoff[c]], &Kl[buf ^ 1][ldoff[c]]);
                    gload16(&vbase[vsoff[c] + (kt + 1) * 64], &Vl[buf ^ 1][ldoff[c]]);
                }
            }
            const unsigned short* Kc = Kl[buf];
            const unsigned short* Vc = Vl[buf];

            const bool act0 = (kt * 64) <= (q0w + 15);
            const bool act1 = (kt * 64) <= (q0w + 31);

            f32x4 s0[4], s1[4];
#pragma unroll
            for (int st = 0; st < 4; ++st) {
                int rbase = (st * 16 + lr) * 64;
                int sw = (lr & 7) ^ (st * 2 + (lr >> 3));
                bf16x8 kf0 = *(const bf16x8*)&Kc[rbase + ((g ^ sw) * 8)];
                bf16x8 kf1 = *(const bf16x8*)&Kc[rbase + (((4 + g) ^ sw) * 8)];
                if (act0) {
                    f32x4 a = {};
                    a = __builtin_amdgcn_mfma_f32_16x16x32_bf16(kf0, *(const bf16x8*)&qf[0][0], a, 0, 0, 0);
                    a = __builtin_amdgcn_mfma_f32_16x16x32_bf16(kf1, *(const bf16x8*)&qf[0][1], a, 0, 0, 0);
                    s0[st] = a;
                }
                if (act1) {
                    f32x4 a = {};
                    a = __builtin_amdgcn_mfma_f32_16x16x32_bf16(kf0, *(const bf16x8*)&qf[1][0], a, 0, 0, 0);
                    a = __builtin_amdgcn_mfma_f32_16x16x32_bf16(kf1, *(const bf16x8*)&qf[1][1], a, 0, 0, 0);
                    s1[st] = a;
                }
            }

            int wt0[2][4], wt1[2][4];
#pragma unroll
            for (int sub = 0; sub < 2; ++sub) {
                if (sub == 0 && !act0) continue;
                if (sub == 1 && !act1) continue;
                f32x4* s = (sub == 0) ? s0 : s1;
                const int qmin = q0w + sub * 16;
                if (kt * 64 + 63 > qmin) {
                    int qv = qmin + lr;
#pragma unroll
                    for (int st = 0; st < 4; ++st) {
                        int keyb = kt * 64 + st * 16 + g * 4;
#pragma unroll
                        for (int r = 0; r < 4; ++r)
                            if (keyb + r > qv) s[st][r] = -3.0e38f;
                    }
                }
                float mx = fmaxf(fmaxf(s[0][0], s[0][1]), fmaxf(s[0][2], s[0][3]));
#pragma unroll
                for (int st = 1; st < 4; ++st)
                    mx = fmaxf(mx, fmaxf(fmaxf(s[st][0], s[st][1]), fmaxf(s[st][2], s[st][3])));
                mx = fmaxf(mx, __shfl_xor(mx, 16));
                mx = fmaxf(mx, __shfl_xor(mx, 32));
                float mold = m_[sub];
                float mnew = fmaxf(mold, mx);
                float alpha = __builtin_amdgcn_exp2f(mold - mnew);
                m_[sub] = mnew;
                float rs = 0.f;
#pragma unroll
                for (int st = 0; st < 4; ++st)
#pragma unroll
                    for (int r = 0; r < 4; ++r) {
                        float pp = __builtin_amdgcn_exp2f(s[st][r] - mnew);
                        s[st][r] = pp;
                        rs += pp;
                    }
                rs += __shfl_xor(rs, 16);
                rs += __shfl_xor(rs, 32);
                l_[sub] = l_[sub] * alpha + rs;
                int av = __builtin_bit_cast(int, alpha);
                f32x4* Os = O[sub];
#pragma unroll
                for (int r = 0; r < 4; ++r) {
                    float ar = __builtin_bit_cast(float, __builtin_amdgcn_ds_bpermute(idxA[r], av));
#pragma unroll
                    for (int dt = 0; dt < 4; ++dt) Os[dt][r] *= ar;
                }
                int ws_[4][2];
#pragma unroll
                for (int st = 0; st < 4; ++st) {
                    ws_[st][0] = cvtpk_bf16(s[st][0], s[st][1]);
                    ws_[st][1] = cvtpk_bf16(s[st][2], s[st][3]);
                }
                int(*wt)[4] = (sub == 0) ? wt0 : wt1;
#pragma unroll
                for (int ks = 0; ks < 2; ++ks)
#pragma unroll
                    for (int hp = 0; hp < 4; ++hp) {
                        int idx = (hp < 2) ? idxP0 : idxP1;
                        int v0 = __builtin_amdgcn_ds_bpermute(idx, ws_[2 * ks][hp & 1]);
                        int v1 = __builtin_amdgcn_ds_bpermute(idx, ws_[2 * ks + 1][hp & 1]);
                        wt[ks][hp] = ghigh ? v1 : v0;
                    }
            }

#pragma unroll
            for (int ks = 0; ks < 2; ++ks) {
                bf16x8 pa0 = *(const bf16x8*)&wt0[ks][0];
                bf16x8 pa1 = *(const bf16x8*)&wt1[ks][0];
#pragma unroll
                for (int dt = 0; dt < 4; ++dt) {
                    int d = dt * 16 + lr;
                    int xv = (ks * 4 + g) ^ (lr & 7) ^ (dt * 2 + (lr >> 3));
                    bf16x8 vf = *(const bf16x8*)&Vc[d * 64 + xv * 8];
                    if (act0) O[0][dt] = __builtin_amdgcn_mfma_f32_16x16x32_bf16(pa0, vf, O[0][dt], 0, 0, 0);
                    if (act1) O[1][dt] = __builtin_amdgcn_mfma_f32_16x16x32_bf16(pa1, vf, O[1][dt], 0, 0, 0);
                }
            }
            buf ^= 1;
        }

#pragma unroll
        for (int sub = 0; sub < 2; ++sub) {
            int lv = __builtin_bit_cast(int, l_[sub]);
#pragma unroll
            for (int r = 0; r < 4; ++r) {
                float lval = __builtin_bit_cast(float, __builtin_amdgcn_ds_bpermute(idxA[r], lv));
                float inv = __builtin_amdgcn_rcpf(lval);
                int q = q0w + sub * 16 + g * 4 + r;
#pragma unroll
                for (int dt = 0; dt < 4; ++dt)
                    y[(size_t)(b * 2048 + q) * 1024 + h * 64 + dt * 16 + lr] =
                        f2bf(O[sub][dt][r] * inv);
            }
        }
    };

    process(15 - p);
    __syncthreads();
    process(p);
}

// ---------------- residual + layernorm: out = base + LN(delta)*g+b ----------------
template <int WRITE_BF>
__global__ __launch_bounds__(256) void ln_kernel(const float* __restrict__ base,
                                                 const float* __restrict__ delta,
                                                 const float* __restrict__ gw,
                                                 const float* __restrict__ bw,
                                                 float* __restrict__ outf,
                                                 unsigned short* __restrict__ outb) {
    const int row = blockIdx.x;
    const int tid = threadIdx.x;
    const float* d = delta + (size_t)row * 1024;
    const float* bs = base + (size_t)row * 1024;
    float4 x = *(const float4*)&d[tid * 4];
    float s = x.x + x.y + x.z + x.w;
    float s2 = x.x * x.x + x.y * x.y + x.z * x.z + x.w * x.w;
#pragma unroll
    for (int off = 1; off < 64; off <<= 1) {
        s += __shfl_xor(s, off);
        s2 += __shfl_xor(s2, off);
    }
    __shared__ float red[8];
    if ((tid & 63) == 0) {
        red[tid >> 6] = s;
        red[4 + (tid >> 6)] = s2;
    }
    __syncthreads();
    s = red[0] + red[1] + red[2] + red[3];
    s2 = red[4] + red[5] + red[6] + red[7];
    float mu = s * (1.f / 1024.f);
    float var = s2 * (1.f / 1024.f) - mu * mu;
    float rsig = rsqrtf(var + 1e-5f);
    float4 bb = *(const float4*)&bs[tid * 4];
    float4 gv = *(const float4*)&gw[tid * 4];
    float4 bv = *(const float4*)&bw[tid * 4];
    float4 o;
    o.x = bb.x + (x.x - mu) * rsig * gv.x + bv.x;
    o.y = bb.y + (x.y - mu) * rsig * gv.y + bv.y;
    o.z = bb.z + (x.z - mu) * rsig * gv.z + bv.z;
    o.w = bb.w + (x.w - mu) * rsig * gv.w + bv.w;
    *(float4*)&outf[(size_t)row * 1024 + tid * 4] = o;
    if (WRITE_BF) {
        unsigned short* ob = outb + (size_t)row * 1024 + tid * 4;
        ob[0] = f2bf(o.x);
        ob[1] = f2bf(o.y);
        ob[2] = f2bf(o.z);
        ob[3] = f2bf(o.w);
    }
}

extern "C" void kernel_launch(void* const* d_in, const int* in_sizes, int n_in,
                              void* d_out, int out_size, void* d_ws, size_t ws_size,
                              hipStream_t stream) {
    const float* x = (const float*)d_in[0];
    const float* w_qkv = (const float*)d_in[1];
    const float* b_qkv = (const float*)d_in[2];
    const float* w_out = (const float*)d_in[3];
    const float* b_out = (const float*)d_in[4];
    const float* w1 = (const float*)d_in[5];
    const float* b1 = (const float*)d_in[6];
    const float* w2 = (const float*)d_in[7];
    const float* b2 = (const float*)d_in[8];
    const float* g1 = (const float*)d_in[9];
    const float* be1 = (const float*)d_in[10];
    const float* g2 = (const float*)d_in[11];
    const float* be2 = (const float*)d_in[12];

    const size_t MB = 1ull << 20;
    if (ws_size < 184 * MB) return;
    char* ws = (char*)d_ws;
    unsigned short* xb    = (unsigned short*)(ws + 0);         // 16MB (dead after qkv gemm)
    unsigned short* vtg   = (unsigned short*)(ws + 0);         // 16MB (V^T, lives during attn)
    unsigned short* wqkvt = (unsigned short*)(ws + 16 * MB);   // 6MB
    unsigned short* qkvb  = (unsigned short*)(ws + 22 * MB);   // 48MB
    unsigned short* hb    = (unsigned short*)(ws + 0);         // 64MB (reuse, MLP phase)
    unsigned short* woutt = (unsigned short*)(ws + 70 * MB);   // 2MB
    unsigned short* yb    = (unsigned short*)(ws + 72 * MB);   // 16MB
    float*          attnp = (float*)(ws + 88 * MB);            // 32MB
    float*          ff    = (float*)(ws + 88 * MB);            // 32MB (reuse)
    float*          x2f   = (float*)(ws + 120 * MB);           // 32MB
    unsigned short* x2b   = (unsigned short*)(ws + 152 * MB);  // 16MB
    unsigned short* w1t   = (unsigned short*)(ws + 168 * MB);  // 8MB
    unsigned short* w2t   = (unsigned short*)(ws + 176 * MB);  // 8MB

    // prep
    cvtbf_kernel<<<8192, 256, 0, stream>>>(x, xb);
    transpose_cvt_kernel<<<dim3(96, 32), dim3(32, 8), 0, stream>>>(w_qkv, wqkvt, 1024, 3072);
    transpose_cvt_kernel<<<dim3(32, 32), dim3(32, 8), 0, stream>>>(w_out, woutt, 1024, 1024);
    transpose_cvt_kernel<<<dim3(128, 32), dim3(32, 8), 0, stream>>>(w1, w1t, 1024, 4096);
    transpose_cvt_kernel<<<dim3(32, 128), dim3(32, 8), 0, stream>>>(w2, w2t, 4096, 1024);
    // qkv = x @ w_qkv + b_qkv (bf16 out) [M=8192 N=3072 K=1024]: 32mt x 12nt
    gemm256_kernel<256, 0, 1><<<384, 512, 0, stream>>>(xb, wqkvt, b_qkv, qkvb, 3072, 1024, 12);
    // V^T pre-transpose
    vtrans_kernel<<<dim3(32, 64), 256, 0, stream>>>(qkvb, vtg);
    // attention
    attn_kernel<<<dim3(8, 16, 4), 256, 0, stream>>>(qkvb, vtg, yb);
    // out proj (f32 out) [N=1024 K=1024]: BM=128 -> 64mt x 4nt
    gemm256_kernel<128, 0, 0><<<256, 512, 0, stream>>>(yb, woutt, b_out, attnp, 1024, 1024, 4);
    // x2 = x + LN(attnp)
    ln_kernel<1><<<8192, 256, 0, stream>>>(x, attnp, g1, be1, x2f, x2b);
    // h = gelu(x2 @ w1 + b1) (bf16 out) [N=4096 K=1024]: 32mt x 16nt
    gemm256_kernel<256, 1, 1><<<512, 512, 0, stream>>>(x2b, w1t, b1, hb, 4096, 1024, 16);
    // f = h @ w2 + b2 (f32 out) [N=1024 K=4096]: BM=128 -> 64mt x 4nt
    gemm256_kernel<128, 0, 0><<<256, 512, 0, stream>>>(hb, w2t, b2, ff, 1024, 4096, 4);
    // out = x2 + LN(f)
    ln_kernel<0><<<8192, 256, 0, stream>>>(x2f, ff, g2, be2, (float*)d_out, nullptr);
}

// Round 7
// 505.434 us; speedup vs baseline: 1.6267x; 1.0122x over previous
//
#include <hip/hip_runtime.h>
#include <hip/hip_bf16.h>

typedef unsigned short ushort_t;
using bf16x8 = __attribute__((ext_vector_type(8))) short;
using f32x4  = __attribute__((ext_vector_type(4))) float;

#define DEV __device__ __forceinline__

DEV unsigned short f2bf(float f) {
    unsigned int u = __builtin_bit_cast(unsigned int, f);
    u = (u + 0x7fffu + ((u >> 16) & 1u)) >> 16;
    return (unsigned short)u;
}

DEV int cvtpk_bf16(float lo, float hi) {
    int r;
    asm("v_cvt_pk_bf16_f32 %0, %1, %2" : "=v"(r) : "v"(lo), "v"(hi));
    return r;
}

DEV void gload16(const unsigned short* g, unsigned short* l) {
    __builtin_amdgcn_global_load_lds(
        (const __attribute__((address_space(1))) void*)g,
        (__attribute__((address_space(3))) void*)l, 16, 0, 0);
}

// tanh-form GELU
DEV float gelu_f(float v) {
    float u = v * (0.79788456f + 0.03567741f * v * v);
    float t = __builtin_amdgcn_exp2f(u * 2.88539008f);
    return v * t * __builtin_amdgcn_rcpf(t + 1.0f);
}

// ---------------- f32 -> bf16 convert ----------------
__global__ __launch_bounds__(256) void cvtbf_kernel(const float* __restrict__ in,
                                                    unsigned short* __restrict__ out) {
    int i = (blockIdx.x * 256 + threadIdx.x) * 4;
    float4 v = *(const float4*)&in[i];
    out[i + 0] = f2bf(v.x);
    out[i + 1] = f2bf(v.y);
    out[i + 2] = f2bf(v.z);
    out[i + 3] = f2bf(v.w);
}

// ---------------- transpose + convert: in[R,C] f32 -> out[C,R] bf16 ----------------
__global__ __launch_bounds__(256) void transpose_cvt_kernel(const float* __restrict__ in,
                                                            unsigned short* __restrict__ out,
                                                            int R, int C) {
    __shared__ float t[32][33];
    int tx = threadIdx.x, ty = threadIdx.y;
    int c0 = blockIdx.x * 32, r0 = blockIdx.y * 32;
#pragma unroll
    for (int i = 0; i < 4; ++i)
        t[ty + i * 8][tx] = in[(size_t)(r0 + ty + i * 8) * C + c0 + tx];
    __syncthreads();
#pragma unroll
    for (int i = 0; i < 4; ++i)
        out[(size_t)(c0 + ty + i * 8) * R + r0 + tx] = f2bf(t[tx][ty + i * 8]);
}

// ---------------- V transpose: qkvb V-part -> vtg[bh][64][2048] bf16 ----------------
__global__ __launch_bounds__(256) void vtrans_kernel(const unsigned short* __restrict__ qkvb,
                                                     unsigned short* __restrict__ vtg) {
    __shared__ unsigned short t[64 * 66];
    const int tid = threadIdx.x;
    const int t0 = blockIdx.x * 64;
    const int bh = blockIdx.y;
    const int b = bh >> 4, h = bh & 15;
    const unsigned short* src = qkvb + (size_t)(b * 2048 + t0) * 3072 + 2048 + h * 64;
#pragma unroll
    for (int c = 0; c < 2; ++c) {
        int cid = c * 256 + tid;
        int row = cid >> 3, cc = cid & 7;
        *(int4*)&t[row * 66 + cc * 8] = *(const int4*)&src[(size_t)row * 3072 + cc * 8];
    }
    __syncthreads();
    unsigned short* dst = vtg + (size_t)bh * 64 * 2048 + t0;
#pragma unroll
    for (int c = 0; c < 2; ++c) {
        int cid = c * 256 + tid;
        int d = cid >> 3, cc2 = cid & 7;
        bf16x8 v;
#pragma unroll
        for (int j = 0; j < 8; ++j) v[j] = (short)t[(cc2 * 8 + j) * 66 + d];
        *(bf16x8*)&dst[(size_t)d * 2048 + cc2 * 8] = v;
    }
}

// ---------------- GEMM 256x256, BK=64, 8 waves (2Mx4N), m201-style 4-phase ----------
// Phase p=(ks,mh): {ds_read 4 af (+4 bfr at mh==0); stage ONE 2-load group of tile
// t+1; barrier; lgkmcnt(0)+SGB; setprio(1); 16 MFMA; setprio(0); [vmcnt(4) at p1/p3];
// barrier}. Groups: p0:{A01} p1:{B01} p2:{A23} p3:{B23}. Every wait drains a group
// issued 2-3 phases earlier; 4 loads stay in flight across all barriers (T3+T4).
template <int ACT, int OBF>
__global__ __launch_bounds__(512, 2) void gemm256_kernel(
    const unsigned short* __restrict__ A, const unsigned short* __restrict__ Bt,
    const float* __restrict__ bias, void* __restrict__ out,
    int N, int K, int gridNt) {
    __shared__ __align__(16) unsigned short lA[2][256 * 64];
    __shared__ __align__(16) unsigned short lB[2][256 * 64];
    const int tid = threadIdx.x;
    const int lane = tid & 63, wid = tid >> 6;
    const int g = lane >> 4, lr = lane & 15;
    const int wm = wid >> 2, wn = wid & 3;

    const int nwg = gridDim.x, cpx = nwg >> 3, bid = blockIdx.x;
    const int wkid = (bid & 7) * cpx + (bid >> 3);
    const int mt = wkid / gridNt, nt = wkid % gridNt;
    const int m0 = mt * 256, n0 = nt * 256;

    auto stageA = [&](int s, int kt, int bb) {  // s in [0,4): covers kb 2s..2s+1
        int c = s * 512 + tid;
        int row = c & 255, kb = c >> 8;
        gload16(&A[(size_t)(m0 + row) * K + kt * 64 + kb * 8],
                &lA[bb][(size_t)(s * 512 + (tid & ~63)) * 8]);
    };
    auto stageB = [&](int s, int kt, int bb) {
        int c = s * 512 + tid;
        int row = c & 255, kb = c >> 8;
        gload16(&Bt[(size_t)(n0 + row) * K + kt * 64 + kb * 8],
                &lB[bb][(size_t)(s * 512 + (tid & ~63)) * 8]);
    };

    f32x4 acc[8][4] = {};
    bf16x8 bfr[4];
    const int nkt = K >> 6;

    // prologue: tile 0 in group order {A01}{B01}{A23}{B23}
    stageA(0, 0, 0); stageA(1, 0, 0); stageB(0, 0, 0); stageB(1, 0, 0);
    stageA(2, 0, 0); stageA(3, 0, 0); stageB(2, 0, 0); stageB(3, 0, 0);
    asm volatile("s_waitcnt vmcnt(4)" ::: "memory");
    __builtin_amdgcn_s_barrier();
    asm volatile("" ::: "memory");

    for (int kt = 0; kt < nkt; ++kt) {
        const int buf = kt & 1;
        const bool more = (kt + 1 < nkt);
#pragma unroll
        for (int p = 0; p < 4; ++p) {
            const int ks = p >> 1, mh = p & 1;
            bf16x8 af[4];
#pragma unroll
            for (int mf2 = 0; mf2 < 4; ++mf2) {
                int c = (ks * 4 + g) * 256 + wm * 128 + (mh * 4 + mf2) * 16 + lr;
                af[mf2] = *(const bf16x8*)&lA[buf][(size_t)c * 8];
            }
            if (mh == 0) {
#pragma unroll
                for (int nf = 0; nf < 4; ++nf) {
                    int c = (ks * 4 + g) * 256 + wn * 64 + nf * 16 + lr;
                    bfr[nf] = *(const bf16x8*)&lB[buf][(size_t)c * 8];
                }
            }
            if (more) {
                if (p == 0)      { stageA(0, kt + 1, buf ^ 1); stageA(1, kt + 1, buf ^ 1); }
                else if (p == 1) { stageB(0, kt + 1, buf ^ 1); stageB(1, kt + 1, buf ^ 1); }
                else if (p == 2) { stageA(2, kt + 1, buf ^ 1); stageA(3, kt + 1, buf ^ 1); }
                else             { stageB(2, kt + 1, buf ^ 1); stageB(3, kt + 1, buf ^ 1); }
            }
            __builtin_amdgcn_s_barrier();
            asm volatile("s_waitcnt lgkmcnt(0)" ::: "memory");
            __builtin_amdgcn_sched_barrier(0);
            __builtin_amdgcn_s_setprio(1);
#pragma unroll
            for (int mf2 = 0; mf2 < 4; ++mf2)
#pragma unroll
                for (int nf = 0; nf < 4; ++nf)
                    acc[mh * 4 + mf2][nf] = __builtin_amdgcn_mfma_f32_16x16x32_bf16(
                        af[mf2], bfr[nf], acc[mh * 4 + mf2][nf], 0, 0, 0);
            __builtin_amdgcn_s_setprio(0);
            __builtin_amdgcn_sched_barrier(0);
            if (p == 1) {
                if (more) asm volatile("s_waitcnt vmcnt(4)" ::: "memory");
                else      asm volatile("s_waitcnt vmcnt(0)" ::: "memory");
            } else if (p == 3) {
                if (more) asm volatile("s_waitcnt vmcnt(4)" ::: "memory");
            }
            __builtin_amdgcn_s_barrier();
            asm volatile("" ::: "memory");
        }
    }

    // epilogue: bias (+GELU) and store; row = m0 + wm*128 + mf*16 + g*4 + r
#pragma unroll
    for (int mf = 0; mf < 8; ++mf) {
#pragma unroll
        for (int nf = 0; nf < 4; ++nf) {
            int col = n0 + wn * 64 + nf * 16 + lr;
            float bv = bias[col];
#pragma unroll
            for (int r = 0; r < 4; ++r) {
                int row = m0 + wm * 128 + mf * 16 + g * 4 + r;
                float v = acc[mf][nf][r] + bv;
                if (ACT == 1) v = gelu_f(v);
                if (OBF)
                    ((unsigned short*)out)[(size_t)row * N + col] = f2bf(v);
                else
                    ((float*)out)[(size_t)row * N + col] = v;
            }
        }
    }
}

// ---------------- GEMM 128x256, BK=64, 8 waves (2Mx4N), 2-phase counted-vmcnt ------
// Phase ks: {ds_read 4 af + 4 bfr; stage 3-load group {A_ks,B_{2ks},B_{2ks+1}}(t+1);
// barrier; lgkmcnt(0)+SGB; setprio; 16 MFMA; setprio; vmcnt(3); barrier}.
template <int ACT, int OBF>
__global__ __launch_bounds__(512, 2) void gemm128_kernel(
    const unsigned short* __restrict__ A, const unsigned short* __restrict__ Bt,
    const float* __restrict__ bias, void* __restrict__ out,
    int N, int K, int gridNt) {
    __shared__ __align__(16) unsigned short lA[2][128 * 64];
    __shared__ __align__(16) unsigned short lB[2][256 * 64];
    const int tid = threadIdx.x;
    const int lane = tid & 63, wid = tid >> 6;
    const int g = lane >> 4, lr = lane & 15;
    const int wm = wid >> 2, wn = wid & 3;

    const int nwg = gridDim.x, cpx = nwg >> 3, bid = blockIdx.x;
    const int wkid = (bid & 7) * cpx + (bid >> 3);
    const int mt = wkid / gridNt, nt = wkid % gridNt;
    const int m0 = mt * 128, n0 = nt * 256;

    auto stageA = [&](int s, int kt, int bb) {  // s in [0,2): covers kb 4s..4s+3
        int c = s * 512 + tid;
        int row = c & 127, kb = c >> 7;
        gload16(&A[(size_t)(m0 + row) * K + kt * 64 + kb * 8],
                &lA[bb][(size_t)(s * 512 + (tid & ~63)) * 8]);
    };
    auto stageB = [&](int s, int kt, int bb) {
        int c = s * 512 + tid;
        int row = c & 255, kb = c >> 8;
        gload16(&Bt[(size_t)(n0 + row) * K + kt * 64 + kb * 8],
                &lB[bb][(size_t)(s * 512 + (tid & ~63)) * 8]);
    };

    f32x4 acc[4][4] = {};
    const int nkt = K >> 6;

    // prologue: tile 0 in group order {A0,B0,B1}{A1,B2,B3}
    stageA(0, 0, 0); stageB(0, 0, 0); stageB(1, 0, 0);
    stageA(1, 0, 0); stageB(2, 0, 0); stageB(3, 0, 0);
    asm volatile("s_waitcnt vmcnt(3)" ::: "memory");
    __builtin_amdgcn_s_barrier();
    asm volatile("" ::: "memory");

    for (int kt = 0; kt < nkt; ++kt) {
        const int buf = kt & 1;
        const bool more = (kt + 1 < nkt);
#pragma unroll
        for (int ks = 0; ks < 2; ++ks) {
            bf16x8 af[4], bfr[4];
#pragma unroll
            for (int mf = 0; mf < 4; ++mf) {
                int c = (ks * 4 + g) * 128 + wm * 64 + mf * 16 + lr;
                af[mf] = *(const bf16x8*)&lA[buf][(size_t)c * 8];
            }
#pragma unroll
            for (int nf = 0; nf < 4; ++nf) {
                int c = (ks * 4 + g) * 256 + wn * 64 + nf * 16 + lr;
                bfr[nf] = *(const bf16x8*)&lB[buf][(size_t)c * 8];
            }
            if (more) {
                if (ks == 0) { stageA(0, kt + 1, buf ^ 1); stageB(0, kt + 1, buf ^ 1); stageB(1, kt + 1, buf ^ 1); }
                else         { stageA(1, kt + 1, buf ^ 1); stageB(2, kt + 1, buf ^ 1); stageB(3, kt + 1, buf ^ 1); }
            }
            __builtin_amdgcn_s_barrier();
            asm volatile("s_waitcnt lgkmcnt(0)" ::: "memory");
            __builtin_amdgcn_sched_barrier(0);
            __builtin_amdgcn_s_setprio(1);
#pragma unroll
            for (int mf = 0; mf < 4; ++mf)
#pragma unroll
                for (int nf = 0; nf < 4; ++nf)
                    acc[mf][nf] = __builtin_amdgcn_mfma_f32_16x16x32_bf16(
                        af[mf], bfr[nf], acc[mf][nf], 0, 0, 0);
            __builtin_amdgcn_s_setprio(0);
            __builtin_amdgcn_sched_barrier(0);
            if (ks == 0) {
                if (more) asm volatile("s_waitcnt vmcnt(3)" ::: "memory");
                else      asm volatile("s_waitcnt vmcnt(0)" ::: "memory");
            } else {
                if (more) asm volatile("s_waitcnt vmcnt(3)" ::: "memory");
            }
            __builtin_amdgcn_s_barrier();
            asm volatile("" ::: "memory");
        }
    }

#pragma unroll
    for (int mf = 0; mf < 4; ++mf) {
#pragma unroll
        for (int nf = 0; nf < 4; ++nf) {
            int col = n0 + wn * 64 + nf * 16 + lr;
            float bv = bias[col];
#pragma unroll
            for (int r = 0; r < 4; ++r) {
                int row = m0 + wm * 64 + mf * 16 + g * 4 + r;
                float v = acc[mf][nf][r] + bv;
                if (ACT == 1) v = gelu_f(v);
                if (OBF)
                    ((unsigned short*)out)[(size_t)row * N + col] = f2bf(v);
                else
                    ((float*)out)[(size_t)row * N + col] = v;
            }
        }
    }
}

// ---------------- flash attention v3 ----------------
__global__ __launch_bounds__(256) void attn_kernel(const unsigned short* __restrict__ qkv,
                                                   const unsigned short* __restrict__ vtg,
                                                   unsigned short* __restrict__ y) {
    __shared__ unsigned short Kl[2][4096];
    __shared__ unsigned short Vl[2][4096];
    const int tid = threadIdx.x, lane = tid & 63, w = tid >> 6;
    const int g = lane >> 4, lr = lane & 15;
    const int p = blockIdx.x, h = blockIdx.y, b = blockIdx.z;
    const int bh = b * 16 + h;
    const size_t rs3 = 3072;
    const unsigned short* qbase = qkv + (size_t)b * 2048 * rs3 + h * 64;
    const unsigned short* kbase = qbase + 1024;
    const unsigned short* vbase = vtg + (size_t)bh * 64 * 2048;

    int ksoff[2], vsoff[2], ldoff[2];
#pragma unroll
    for (int c = 0; c < 2; ++c) {
        int row = w * 16 + c * 8 + (lane >> 3);
        int ccs = (lane & 7) ^ (row & 7) ^ (row >> 3);
        ksoff[c] = row * 3072 + ccs * 8;
        vsoff[c] = row * 2048 + ccs * 8;
        ldoff[c] = (w * 16 + c * 8) * 64;
    }

    const int idxP0 = 4 * (32 * (g & 1) + lr);
    const int idxP1 = idxP0 + 64;
    int idxA[4];
#pragma unroll
    for (int r = 0; r < 4; ++r) idxA[r] = 4 * (g * 20 + r);
    const bool ghigh = (g >> 1) != 0;
    const float qscale = 0.125f * 1.44269504089f;

    auto process = [&](int J) {
        const int q0w = J * 128 + w * 32;
        const int ktend = 2 * J + 2;
#pragma unroll
        for (int c = 0; c < 2; ++c) {
            gload16(&kbase[ksoff[c]], &Kl[0][ldoff[c]]);
            gload16(&vbase[vsoff[c]], &Vl[0][ldoff[c]]);
        }
        int qf[2][2][4];
#pragma unroll
        for (int sub = 0; sub < 2; ++sub)
#pragma unroll
            for (int f = 0; f < 2; ++f) {
                int4 v = *(const int4*)&qbase[(size_t)(q0w + sub * 16 + lr) * rs3 + f * 32 + g * 8];
                int vv[4] = {v.x, v.y, v.z, v.w};
#pragma unroll
                for (int i = 0; i < 4; ++i) {
                    unsigned int u = (unsigned int)vv[i];
                    float lo = __builtin_bit_cast(float, u << 16) * qscale;
                    float hi = __builtin_bit_cast(float, u & 0xffff0000u) * qscale;
                    qf[sub][f][i] = cvtpk_bf16(lo, hi);
                }
            }

        f32x4 O[2][4] = {};
        float m_[2] = {-3.0e38f, -3.0e38f}, l_[2] = {0.f, 0.f};

        int buf = 0;
        for (int kt = 0; kt < ktend; ++kt) {
            asm volatile("s_waitcnt vmcnt(0)" ::: "memory");
            __builtin_amdgcn_s_barrier();
            asm volatile("" ::: "memory");
            if (kt + 1 < ktend) {
#pragma unroll
                for (int c = 0; c < 2; ++c) {
                    gload16(&kbase[(size_t)(kt + 1) * 64 * 3072 + ksoff[c]], &Kl[buf ^ 1][ldoff[c]]);
                    gload16(&vbase[vsoff[c] + (kt + 1) * 64], &Vl[buf ^ 1][ldoff[c]]);
                }
            }
            const unsigned short* Kc = Kl[buf];
            const unsigned short* Vc = Vl[buf];

            const bool act0 = (kt * 64) <= (q0w + 15);
            const bool act1 = (kt * 64) <= (q0w + 31);

            f32x4 s0[4], s1[4];
#pragma unroll
            for (int st = 0; st < 4; ++st) {
                int rbase = (st * 16 + lr) * 64;
                int sw = (lr & 7) ^ (st * 2 + (lr >> 3));
                bf16x8 kf0 = *(const bf16x8*)&Kc[rbase + ((g ^ sw) * 8)];
                bf16x8 kf1 = *(const bf16x8*)&Kc[rbase + (((4 + g) ^ sw) * 8)];
                if (act0) {
                    f32x4 a = {};
                    a = __builtin_amdgcn_mfma_f32_16x16x32_bf16(kf0, *(const bf16x8*)&qf[0][0], a, 0, 0, 0);
                    a = __builtin_amdgcn_mfma_f32_16x16x32_bf16(kf1, *(const bf16x8*)&qf[0][1], a, 0, 0, 0);
                    s0[st] = a;
                }
                if (act1) {
                    f32x4 a = {};
                    a = __builtin_amdgcn_mfma_f32_16x16x32_bf16(kf0, *(const bf16x8*)&qf[1][0], a, 0, 0, 0);
                    a = __builtin_amdgcn_mfma_f32_16x16x32_bf16(kf1, *(const bf16x8*)&qf[1][1], a, 0, 0, 0);
                    s1[st] = a;
                }
            }

            int wt0[2][4], wt1[2][4];
#pragma unroll
            for (int sub = 0; sub < 2; ++sub) {
                if (sub == 0 && !act0) continue;
                if (sub == 1 && !act1) continue;
                f32x4* s = (sub == 0) ? s0 : s1;
                const int qmin = q0w + sub * 16;
                if (kt * 64 + 63 > qmin) {
                    int qv = qmin + lr;
#pragma unroll
                    for (int st = 0; st < 4; ++st) {
                        int keyb = kt * 64 + st * 16 + g * 4;
#pragma unroll
                        for (int r = 0; r < 4; ++r)
                            if (keyb + r > qv) s[st][r] = -3.0e38f;
                    }
                }
                float mx = fmaxf(fmaxf(s[0][0], s[0][1]), fmaxf(s[0][2], s[0][3]));
#pragma unroll
                for (int st = 1; st < 4; ++st)
                    mx = fmaxf(mx, fmaxf(fmaxf(s[st][0], s[st][1]), fmaxf(s[st][2], s[st][3])));
                mx = fmaxf(mx, __shfl_xor(mx, 16));
                mx = fmaxf(mx, __shfl_xor(mx, 32));
                float mold = m_[sub];
                float mnew = fmaxf(mold, mx);
                float alpha = __builtin_amdgcn_exp2f(mold - mnew);
                m_[sub] = mnew;
                float rs = 0.f;
#pragma unroll
                for (int st = 0; st < 4; ++st)
#pragma unroll
                    for (int r = 0; r < 4; ++r) {
                        float pp = __builtin_amdgcn_exp2f(s[st][r] - mnew);
                        s[st][r] = pp;
                        rs += pp;
                    }
                rs += __shfl_xor(rs, 16);
                rs += __shfl_xor(rs, 32);
                l_[sub] = l_[sub] * alpha + rs;
                int av = __builtin_bit_cast(int, alpha);
                f32x4* Os = O[sub];
#pragma unroll
                for (int r = 0; r < 4; ++r) {
                    float ar = __builtin_bit_cast(float, __builtin_amdgcn_ds_bpermute(idxA[r], av));
#pragma unroll
                    for (int dt = 0; dt < 4; ++dt) Os[dt][r] *= ar;
                }
                int ws_[4][2];
#pragma unroll
                for (int st = 0; st < 4; ++st) {
                    ws_[st][0] = cvtpk_bf16(s[st][0], s[st][1]);
                    ws_[st][1] = cvtpk_bf16(s[st][2], s[st][3]);
                }
                int(*wt)[4] = (sub == 0) ? wt0 : wt1;
#pragma unroll
                for (int ks = 0; ks < 2; ++ks)
#pragma unroll
                    for (int hp = 0; hp < 4; ++hp) {
                        int idx = (hp < 2) ? idxP0 : idxP1;
                        int v0 = __builtin_amdgcn_ds_bpermute(idx, ws_[2 * ks][hp & 1]);
                        int v1 = __builtin_amdgcn_ds_bpermute(idx, ws_[2 * ks + 1][hp & 1]);
                        wt[ks][hp] = ghigh ? v1 : v0;
                    }
            }

#pragma unroll
            for (int ks = 0; ks < 2; ++ks) {
                bf16x8 pa0 = *(const bf16x8*)&wt0[ks][0];
                bf16x8 pa1 = *(const bf16x8*)&wt1[ks][0];
#pragma unroll
                for (int dt = 0; dt < 4; ++dt) {
                    int d = dt * 16 + lr;
                    int xv = (ks * 4 + g) ^ (lr & 7) ^ (dt * 2 + (lr >> 3));
                    bf16x8 vf = *(const bf16x8*)&Vc[d * 64 + xv * 8];
                    if (act0) O[0][dt] = __builtin_amdgcn_mfma_f32_16x16x32_bf16(pa0, vf, O[0][dt], 0, 0, 0);
                    if (act1) O[1][dt] = __builtin_amdgcn_mfma_f32_16x16x32_bf16(pa1, vf, O[1][dt], 0, 0, 0);
                }
            }
            buf ^= 1;
        }

#pragma unroll
        for (int sub = 0; sub < 2; ++sub) {
            int lv = __builtin_bit_cast(int, l_[sub]);
#pragma unroll
            for (int r = 0; r < 4; ++r) {
                float lval = __builtin_bit_cast(float, __builtin_amdgcn_ds_bpermute(idxA[r], lv));
                float inv = __builtin_amdgcn_rcpf(lval);
                int q = q0w + sub * 16 + g * 4 + r;
#pragma unroll
                for (int dt = 0; dt < 4; ++dt)
                    y[(size_t)(b * 2048 + q) * 1024 + h * 64 + dt * 16 + lr] =
                        f2bf(O[sub][dt][r] * inv);
            }
        }
    };

    process(15 - p);
    __syncthreads();
    process(p);
}

// ---------------- residual + layernorm: out = base + LN(delta)*g+b ----------------
template <int WRITE_BF>
__global__ __launch_bounds__(256) void ln_kernel(const float* __restrict__ base,
                                                 const float* __restrict__ delta,
                                                 const float* __restrict__ gw,
                                                 const float* __restrict__ bw,
                                                 float* __restrict__ outf,
                                                 unsigned short* __restrict__ outb) {
    const int row = blockIdx.x;
    const int tid = threadIdx.x;
    const float* d = delta + (size_t)row * 1024;
    const float* bs = base + (size_t)row * 1024;
    float4 x = *(const float4*)&d[tid * 4];
    float s = x.x + x.y + x.z + x.w;
    float s2 = x.x * x.x + x.y * x.y + x.z * x.z + x.w * x.w;
#pragma unroll
    for (int off = 1; off < 64; off <<= 1) {
        s += __shfl_xor(s, off);
        s2 += __shfl_xor(s2, off);
    }
    __shared__ float red[8];
    if ((tid & 63) == 0) {
        red[tid >> 6] = s;
        red[4 + (tid >> 6)] = s2;
    }
    __syncthreads();
    s = red[0] + red[1] + red[2] + red[3];
    s2 = red[4] + red[5] + red[6] + red[7];
    float mu = s * (1.f / 1024.f);
    float var = s2 * (1.f / 1024.f) - mu * mu;
    float rsig = rsqrtf(var + 1e-5f);
    float4 bb = *(const float4*)&bs[tid * 4];
    float4 gv = *(const float4*)&gw[tid * 4];
    float4 bv = *(const float4*)&bw[tid * 4];
    float4 o;
    o.x = bb.x + (x.x - mu) * rsig * gv.x + bv.x;
    o.y = bb.y + (x.y - mu) * rsig * gv.y + bv.y;
    o.z = bb.z + (x.z - mu) * rsig * gv.z + bv.z;
    o.w = bb.w + (x.w - mu) * rsig * gv.w + bv.w;
    *(float4*)&outf[(size_t)row * 1024 + tid * 4] = o;
    if (WRITE_BF) {
        unsigned short* ob = outb + (size_t)row * 1024 + tid * 4;
        ob[0] = f2bf(o.x);
        ob[1] = f2bf(o.y);
        ob[2] = f2bf(o.z);
        ob[3] = f2bf(o.w);
    }
}

extern "C" void kernel_launch(void* const* d_in, const int* in_sizes, int n_in,
                              void* d_out, int out_size, void* d_ws, size_t ws_size,
                              hipStream_t stream) {
    const float* x = (const float*)d_in[0];
    const float* w_qkv = (const float*)d_in[1];
    const float* b_qkv = (const float*)d_in[2];
    const float* w_out = (const float*)d_in[3];
    const float* b_out = (const float*)d_in[4];
    const float* w1 = (const float*)d_in[5];
    const float* b1 = (const float*)d_in[6];
    const float* w2 = (const float*)d_in[7];
    const float* b2 = (const float*)d_in[8];
    const float* g1 = (const float*)d_in[9];
    const float* be1 = (const float*)d_in[10];
    const float* g2 = (const float*)d_in[11];
    const float* be2 = (const float*)d_in[12];

    const size_t MB = 1ull << 20;
    if (ws_size < 184 * MB) return;
    char* ws = (char*)d_ws;
    unsigned short* xb    = (unsigned short*)(ws + 0);         // 16MB (dead after qkv gemm)
    unsigned short* vtg   = (unsigned short*)(ws + 0);         // 16MB (V^T, lives during attn)
    unsigned short* wqkvt = (unsigned short*)(ws + 16 * MB);   // 6MB
    unsigned short* qkvb  = (unsigned short*)(ws + 22 * MB);   // 48MB
    unsigned short* hb    = (unsigned short*)(ws + 0);         // 64MB (reuse, MLP phase)
    unsigned short* woutt = (unsigned short*)(ws + 70 * MB);   // 2MB
    unsigned short* yb    = (unsigned short*)(ws + 72 * MB);   // 16MB
    float*          attnp = (float*)(ws + 88 * MB);            // 32MB
    float*          ff    = (float*)(ws + 88 * MB);            // 32MB (reuse)
    float*          x2f   = (float*)(ws + 120 * MB);           // 32MB
    unsigned short* x2b   = (unsigned short*)(ws + 152 * MB);  // 16MB
    unsigned short* w1t   = (unsigned short*)(ws + 168 * MB);  // 8MB
    unsigned short* w2t   = (unsigned short*)(ws + 176 * MB);  // 8MB

    // prep
    cvtbf_kernel<<<8192, 256, 0, stream>>>(x, xb);
    transpose_cvt_kernel<<<dim3(96, 32), dim3(32, 8), 0, stream>>>(w_qkv, wqkvt, 1024, 3072);
    transpose_cvt_kernel<<<dim3(32, 32), dim3(32, 8), 0, stream>>>(w_out, woutt, 1024, 1024);
    transpose_cvt_kernel<<<dim3(128, 32), dim3(32, 8), 0, stream>>>(w1, w1t, 1024, 4096);
    transpose_cvt_kernel<<<dim3(32, 128), dim3(32, 8), 0, stream>>>(w2, w2t, 4096, 1024);
    // qkv = x @ w_qkv + b_qkv (bf16 out) [M=8192 N=3072 K=1024]: 32mt x 12nt
    gemm256_kernel<0, 1><<<384, 512, 0, stream>>>(xb, wqkvt, b_qkv, qkvb, 3072, 1024, 12);
    // V^T pre-transpose
    vtrans_kernel<<<dim3(32, 64), 256, 0, stream>>>(qkvb, vtg);
    // attention
    attn_kernel<<<dim3(8, 16, 4), 256, 0, stream>>>(qkvb, vtg, yb);
    // out proj (f32 out) [N=1024 K=1024]: 64mt x 4nt
    gemm128_kernel<0, 0><<<256, 512, 0, stream>>>(yb, woutt, b_out, attnp, 1024, 1024, 4);
    // x2 = x + LN(attnp)
    ln_kernel<1><<<8192, 256, 0, stream>>>(x, attnp, g1, be1, x2f, x2b);
    // h = gelu(x2 @ w1 + b1) (bf16 out) [N=4096 K=1024]: 32mt x 16nt
    gemm256_kernel<1, 1><<<512, 512, 0, stream>>>(x2b, w1t, b1, hb, 4096, 1024, 16);
    // f = h @ w2 + b2 (f32 out) [N=1024 K=4096]: 64mt x 4nt
    gemm128_kernel<0, 0><<<256, 512, 0, stream>>>(hb, w2t, b2, ff, 1024, 4096, 4);
    // out = x2 + LN(f)
    ln_kernel<0><<<8192, 256, 0, stream>>>(x2f, ff, g2, be2, (float*)d_out, nullptr);
}